// Round 4
// baseline (728.652 us; speedup 1.0000x reference)
//
#include <hip/hip_runtime.h>
#include <hip/hip_bf16.h>

typedef __bf16 bf16x8 __attribute__((ext_vector_type(8)));
typedef float  f32x4  __attribute__((ext_vector_type(4)));

static constexpr int N_ROWS  = 262144;
static constexpr int K_CODES = 1024;
static constexpr int D_DIM   = 64;

// d_out layout (floats): z_q_st[N*D], vq_loss, indices[N], z_q[N*D]
static constexpr long LOSS_OFF = (long)N_ROWS * D_DIM;   // 16777216
static constexpr long IDX_OFF  = LOSS_OFF + 1;           // 16777217
static constexpr long ZQ_OFF   = IDX_OFF + N_ROWS;       // 17039361

// ws byte layout
static constexpr size_t CSQ_B   = 0;                              // f32[1024]
static constexpr size_t BFRAG_B = 4096;                           // 16 tiles * 16 KB
static constexpr size_t CNT_B   = BFRAG_B + (size_t)16 * 16384;   // 266240
static constexpr size_t PART_B  = CNT_B + 256;                    // 266496: f32[1024]
static constexpr size_t LIST_B  = PART_B + 4096;                  // 270592: int/f32[N]
static constexpr size_t WS_NEEDED = LIST_B + (size_t)N_ROWS * 4;  // ~1.32 MB

static constexpr float MARGIN = 0.05f;
static constexpr int   EPI_BLOCKS = (N_ROWS * D_DIM) / (256 * 4); // fallback only

#define GLOAD_LDS16(g, l) __builtin_amdgcn_global_load_lds( \
    (const __attribute__((address_space(1))) unsigned int*)(g), \
    (__attribute__((address_space(3))) unsigned int*)(l), 16, 0, 0)

// ---------------- fused prep: csq + bf16 hi/lo fragments + cnt zero ----------
__global__ __launch_bounds__(256) void fusedprep_kernel(const float* __restrict__ cb,
                                                        char* __restrict__ wsb) {
    const int t = blockIdx.x * 256 + threadIdx.x;   // 0..8191 = c*8 + ks*4 + g
    if (t == 0) *(int*)(wsb + CNT_B) = 0;

    // csq: EXACT same arithmetic order as rounds 1-3 (argmin consistency)
    if (t < K_CODES) {
        const float4* row = reinterpret_cast<const float4*>(cb) + (size_t)t * (D_DIM / 4);
        float s = 0.f;
        #pragma unroll
        for (int j = 0; j < D_DIM / 4; ++j) {
            float4 v = row[j];
            s = fmaf(v.x, v.x, s); s = fmaf(v.y, v.y, s);
            s = fmaf(v.z, v.z, s); s = fmaf(v.w, v.w, s);
        }
        ((float*)(wsb + CSQ_B))[t] = s;
    }

    // fragment split: B-frag lane l supplies B[k][n], n=l&15, k=32*ks+8*(l>>4)+i
    const int c  = t >> 3;
    const int ks = (t >> 2) & 1;
    const int g  = t & 3;
    const float* src = cb + (size_t)c * 64 + ks * 32 + g * 8;
    float f[8];
    #pragma unroll
    for (int i = 0; i < 8; ++i) f[i] = src[i];
    bf16x8 h, l;
    #pragma unroll
    for (int i = 0; i < 8; ++i) {
        __bf16 hv = (__bf16)f[i];
        h[i] = hv;
        l[i] = (__bf16)(f[i] - (float)hv);
    }
    const int tile = c >> 6, cf = (c >> 4) & 3, n = c & 15;
    const int lane = g * 16 + n;
    char* base = wsb + BFRAG_B + (size_t)tile * 16384;
    *reinterpret_cast<bf16x8*>(base + ((0 * 2 + ks) * 4 + cf) * 1024 + lane * 16) = h;
    *reinterpret_cast<bf16x8*>(base + ((1 * 2 + ks) * 4 + cf) * 1024 + lane * 16) = l;
}

// ---------------- main: MFMA argmin + fused gather/store/loss epilogue ------
__global__ __launch_bounds__(256, 4) void vq_gemm_kernel(const float* __restrict__ z,
                                                         const float* __restrict__ cb,
                                                         char* __restrict__ wsb,
                                                         float* __restrict__ out) {
    __shared__ __align__(16) unsigned char sbuf[2 * 16384 + 4096];
    float* lds_csq = (float*)(sbuf + 32768);                 // reused as idx_sh later
    int*   idx_sh  = (int*)(sbuf + 32768);
    float* bsum    = (float*)(sbuf + 32768 + 1024);

    const int tid  = threadIdx.x;
    const int lane = tid & 63, wid = tid >> 6;
    const int l15  = lane & 15, lg = lane >> 4;

    const float* csq = (const float*)(wsb + CSQ_B);
    #pragma unroll
    for (int i = 0; i < 4; ++i) lds_csq[tid + 256 * i] = csq[tid + 256 * i];

    // A fragments: lane l supplies A[m][k], m = l&15, k = 32*ks + 8*(l>>4)+i
    const int rowbase = blockIdx.x * 256 + wid * 64;
    bf16x8 ah[4][2], al[4][2];
    #pragma unroll
    for (int rf = 0; rf < 4; ++rf) {
        const float* zr = z + (size_t)(rowbase + rf * 16 + l15) * 64 + lg * 8;
        #pragma unroll
        for (int ks = 0; ks < 2; ++ks) {
            float4 a = *reinterpret_cast<const float4*>(zr + ks * 32);
            float4 b = *reinterpret_cast<const float4*>(zr + ks * 32 + 4);
            float f[8] = {a.x, a.y, a.z, a.w, b.x, b.y, b.z, b.w};
            bf16x8 h, l;
            #pragma unroll
            for (int i = 0; i < 8; ++i) {
                __bf16 hv = (__bf16)f[i];
                h[i] = hv;
                l[i] = (__bf16)(f[i] - (float)hv);
            }
            ah[rf][ks] = h; al[rf][ks] = l;
        }
    }

    float m1[16], m2[16]; int i1[16];
    #pragma unroll
    for (int s = 0; s < 16; ++s) { m1[s] = INFINITY; m2[s] = INFINITY; i1[s] = 0; }

    const char* bsrc = wsb + BFRAG_B;
    auto stage = [&](int buf, int t) {
        const char* src = bsrc + (size_t)t * 16384;
        #pragma unroll
        for (int it = 0; it < 4; ++it) {
            GLOAD_LDS16(src + it * 4096 + wid * 1024 + lane * 16,
                        sbuf + buf * 16384 + it * 4096 + wid * 1024);
        }
    };

    stage(0, 0);
    __syncthreads();

    for (int t = 0; t < 16; ++t) {
        if (t < 15) stage((t + 1) & 1, t + 1);
        const unsigned char* B = sbuf + (t & 1) * 16384;
        #pragma unroll
        for (int cf = 0; cf < 4; ++cf) {
            bf16x8 bh0 = *reinterpret_cast<const bf16x8*>(B + (0 * 4 + cf) * 1024 + lane * 16);
            bf16x8 bh1 = *reinterpret_cast<const bf16x8*>(B + (1 * 4 + cf) * 1024 + lane * 16);
            bf16x8 bl0 = *reinterpret_cast<const bf16x8*>(B + (2 * 4 + cf) * 1024 + lane * 16);
            bf16x8 bl1 = *reinterpret_cast<const bf16x8*>(B + (3 * 4 + cf) * 1024 + lane * 16);
            const int code = t * 64 + cf * 16 + l15;
            const float cq = lds_csq[code];
            #pragma unroll
            for (int rf = 0; rf < 4; ++rf) {
                f32x4 acc = {0.f, 0.f, 0.f, 0.f};
                acc = __builtin_amdgcn_mfma_f32_16x16x32_bf16(ah[rf][0], bh0, acc, 0, 0, 0);
                acc = __builtin_amdgcn_mfma_f32_16x16x32_bf16(ah[rf][1], bh1, acc, 0, 0, 0);
                acc = __builtin_amdgcn_mfma_f32_16x16x32_bf16(al[rf][0], bh0, acc, 0, 0, 0);
                acc = __builtin_amdgcn_mfma_f32_16x16x32_bf16(al[rf][1], bh1, acc, 0, 0, 0);
                acc = __builtin_amdgcn_mfma_f32_16x16x32_bf16(ah[rf][0], bl0, acc, 0, 0, 0);
                acc = __builtin_amdgcn_mfma_f32_16x16x32_bf16(ah[rf][1], bl1, acc, 0, 0, 0);
                #pragma unroll
                for (int r = 0; r < 4; ++r) {
                    float dist = fmaf(-2.f, acc[r], cq);
                    int s = rf * 4 + r;
                    bool lt = dist < m1[s];
                    m2[s] = fminf(m2[s], fmaxf(dist, m1[s]));
                    m1[s] = fminf(m1[s], dist);
                    i1[s] = lt ? code : i1[s];
                }
            }
        }
        __syncthreads();
    }

    // merge across the 16 lanes of each lane-group
    #pragma unroll
    for (int s = 0; s < 16; ++s) {
        #pragma unroll
        for (int off = 1; off < 16; off <<= 1) {
            float om1 = __shfl_xor(m1[s], off);
            float om2 = __shfl_xor(m2[s], off);
            int   oi  = __shfl_xor(i1[s], off);
            bool lt = (om1 < m1[s]) || (om1 == m1[s] && oi < i1[s]);
            m2[s] = fminf(fminf(m2[s], om2), fmaxf(m1[s], om1));
            m1[s] = fminf(m1[s], om1);
            i1[s] = lt ? oi : i1[s];
        }
    }

    if (l15 == 0) {
        int* cnt  = (int*)(wsb + CNT_B);
        int* list = (int*)(wsb + LIST_B);
        #pragma unroll
        for (int rf = 0; rf < 4; ++rf) {
            #pragma unroll
            for (int r = 0; r < 4; ++r) {
                int s = rf * 4 + r;
                int row = rowbase + rf * 16 + lg * 4 + r;
                out[IDX_OFF + row] = (float)i1[s];
                idx_sh[wid * 64 + rf * 16 + lg * 4 + r] = i1[s];
                if (m2[s] - m1[s] < MARGIN) {
                    int pos = atomicAdd(cnt, 1);
                    list[pos] = row;
                }
            }
        }
    }
    __syncthreads();   // idx_sh visible; csq region no longer needed

    // fused epilogue: this wave's 64 rows -> z_q_st, z_q, loss partial
    float lsum = 0.f;
    #pragma unroll 4
    for (int rl = 0; rl < 64; ++rl) {
        const int row = rowbase + rl;
        const int k   = idx_sh[wid * 64 + rl];
        float zv = z [(size_t)row * 64 + lane];
        float cv = cb[(size_t)k   * 64 + lane];
        out[(size_t)row * 64 + lane]          = zv + (cv - zv);   // z_q_st (ref formula)
        out[ZQ_OFF + (size_t)row * 64 + lane] = cv;               // z_q
        float d = cv - zv;
        lsum = fmaf(d, d, lsum);
    }
    #pragma unroll
    for (int off = 32; off > 0; off >>= 1) lsum += __shfl_down(lsum, off, 64);
    if (lane == 0) bsum[wid] = lsum;
    __syncthreads();
    if (tid == 0)
        ((float*)(wsb + PART_B))[blockIdx.x] = (bsum[0] + bsum[1]) + (bsum[2] + bsum[3]);
}

// ---------------- exact fp32 re-argmin + output fix for flagged rows --------
__global__ __launch_bounds__(256) void rescore_kernel(const float* __restrict__ z,
                                                      const float* __restrict__ cb,
                                                      char* __restrict__ wsb,
                                                      float* __restrict__ out) {
    const int lane = threadIdx.x & 63;
    const int wgid = (blockIdx.x * 256 + threadIdx.x) >> 6;
    int cnt = *(const int*)(wsb + CNT_B);
    if (cnt > N_ROWS) cnt = N_ROWS;
    int*         list = (int*)(wsb + LIST_B);
    const float* csq  = (const float*)(wsb + CSQ_B);

    for (int i = wgid; i < cnt; i += 256 * 4) {
        const int row  = list[i];
        const int kold = (int)out[IDX_OFF + row];

        float4 zr[16];
        const float4* zp = reinterpret_cast<const float4*>(z) + (size_t)row * 16;
        #pragma unroll
        for (int j = 0; j < 16; ++j) zr[j] = zp[j];
        float best = INFINITY; int bi = 0;
        for (int k = lane; k < K_CODES; k += 64) {
            const float4* cp = reinterpret_cast<const float4*>(cb) + (size_t)k * 16;
            float d0 = 0.f, d1 = 0.f, d2 = 0.f, d3 = 0.f;
            #pragma unroll
            for (int j = 0; j < 16; j += 4) {
                float4 c0 = cp[j + 0], c1 = cp[j + 1], c2 = cp[j + 2], c3 = cp[j + 3];
                d0 = fmaf(zr[j+0].x, c0.x, fmaf(zr[j+0].y, c0.y, fmaf(zr[j+0].z, c0.z, fmaf(zr[j+0].w, c0.w, d0))));
                d1 = fmaf(zr[j+1].x, c1.x, fmaf(zr[j+1].y, c1.y, fmaf(zr[j+1].z, c1.z, fmaf(zr[j+1].w, c1.w, d1))));
                d2 = fmaf(zr[j+2].x, c2.x, fmaf(zr[j+2].y, c2.y, fmaf(zr[j+2].z, c2.z, fmaf(zr[j+2].w, c2.w, d2))));
                d3 = fmaf(zr[j+3].x, c3.x, fmaf(zr[j+3].y, c3.y, fmaf(zr[j+3].z, c3.z, fmaf(zr[j+3].w, c3.w, d3))));
            }
            float dist = fmaf(-2.f, (d0 + d1) + (d2 + d3), csq[k]);
            if (dist < best) { best = dist; bi = k; }
        }
        #pragma unroll
        for (int off = 1; off < 64; off <<= 1) {
            float ob = __shfl_xor(best, off);
            int   oi = __shfl_xor(bi, off);
            if (ob < best || (ob == best && oi < bi)) { best = ob; bi = oi; }
        }

        // fix outputs + deterministic loss delta (elementwise, same form as epilogue)
        float zv   = z [(size_t)row  * 64 + lane];
        float cold = cb[(size_t)kold * 64 + lane];
        float cnew = cb[(size_t)bi   * 64 + lane];
        out[(size_t)row * 64 + lane]          = zv + (cnew - zv);
        out[ZQ_OFF + (size_t)row * 64 + lane] = cnew;
        float dn = cnew - zv, dol = cold - zv;
        float pn = dn * dn, po = dol * dol;
        #pragma unroll
        for (int off = 32; off > 0; off >>= 1) {
            pn += __shfl_down(pn, off, 64);
            po += __shfl_down(po, off, 64);
        }
        if (lane == 0) {
            out[IDX_OFF + row] = (float)bi;
            ((float*)list)[i]  = pn - po;   // overwrite slot with loss delta
        }
    }
}

// ---------------- loss finalize ---------------------------------------------
__global__ __launch_bounds__(256) void loss_kernel(const char* __restrict__ wsb,
                                                   float* __restrict__ out) {
    const float* part = (const float*)(wsb + PART_B);
    int cnt = *(const int*)(wsb + CNT_B);
    if (cnt > N_ROWS) cnt = N_ROWS;
    const float* delta = (const float*)(wsb + LIST_B);

    double s = 0.0;
    for (int i = threadIdx.x; i < 1024; i += 256) s += (double)part[i];
    for (int i = threadIdx.x; i < cnt;  i += 256) s += (double)delta[i];
    #pragma unroll
    for (int off = 32; off > 0; off >>= 1) s += __shfl_down(s, off, 64);

    __shared__ double dsum[4];
    const int lane = threadIdx.x & 63, wid = threadIdx.x >> 6;
    if (lane == 0) dsum[wid] = s;
    __syncthreads();
    if (threadIdx.x == 0) {
        double total = (dsum[0] + dsum[1]) + (dsum[2] + dsum[3]);
        out[LOSS_OFF] = (float)(1.25 * (total / (double)((long)N_ROWS * D_DIM)));
    }
}

// ---------------- fallback path (round-1, known-good) ------------------------
__global__ __launch_bounds__(256) void csq_kernel(const float* __restrict__ cb,
                                                  float* __restrict__ ws) {
    int g = blockIdx.x * 256 + threadIdx.x;
    const float4* row = reinterpret_cast<const float4*>(cb) + (size_t)g * (D_DIM / 4);
    float s = 0.f;
    #pragma unroll
    for (int j = 0; j < D_DIM / 4; ++j) {
        float4 v = row[j];
        s = fmaf(v.x, v.x, s); s = fmaf(v.y, v.y, s);
        s = fmaf(v.z, v.z, s); s = fmaf(v.w, v.w, s);
    }
    ws[g] = s;
}

__global__ __launch_bounds__(256) void argmin_old_kernel(const float* __restrict__ z,
                                                         const float* __restrict__ cb,
                                                         const float* __restrict__ ws,
                                                         float* __restrict__ out) {
    __shared__ float4 tile[64 * 16];
    __shared__ float  csq_sh[64];
    const int row = blockIdx.x * 256 + threadIdx.x;
    float4 zr[16];
    const float4* zp = reinterpret_cast<const float4*>(z) + (size_t)row * 16;
    #pragma unroll
    for (int j = 0; j < 16; ++j) zr[j] = zp[j];
    float best = __builtin_inff();
    int   bidx = 0;
    for (int k0 = 0; k0 < K_CODES; k0 += 64) {
        __syncthreads();
        const float4* src = reinterpret_cast<const float4*>(cb) + (size_t)k0 * 16;
        #pragma unroll
        for (int j = 0; j < 4; ++j)
            tile[threadIdx.x + 256 * j] = src[threadIdx.x + 256 * j];
        if (threadIdx.x < 64) csq_sh[threadIdx.x] = ws[k0 + threadIdx.x];
        __syncthreads();
        #pragma unroll 2
        for (int k = 0; k < 64; ++k) {
            float d0 = 0.f, d1 = 0.f, d2 = 0.f, d3 = 0.f;
            #pragma unroll
            for (int j = 0; j < 16; j += 4) {
                float4 c0 = tile[k*16+j+0], c1 = tile[k*16+j+1], c2 = tile[k*16+j+2], c3 = tile[k*16+j+3];
                d0 = fmaf(zr[j+0].x, c0.x, fmaf(zr[j+0].y, c0.y, fmaf(zr[j+0].z, c0.z, fmaf(zr[j+0].w, c0.w, d0))));
                d1 = fmaf(zr[j+1].x, c1.x, fmaf(zr[j+1].y, c1.y, fmaf(zr[j+1].z, c1.z, fmaf(zr[j+1].w, c1.w, d1))));
                d2 = fmaf(zr[j+2].x, c2.x, fmaf(zr[j+2].y, c2.y, fmaf(zr[j+2].z, c2.z, fmaf(zr[j+2].w, c2.w, d2))));
                d3 = fmaf(zr[j+3].x, c3.x, fmaf(zr[j+3].y, c3.y, fmaf(zr[j+3].z, c3.z, fmaf(zr[j+3].w, c3.w, d3))));
            }
            float dist = fmaf(-2.f, (d0 + d1) + (d2 + d3), csq_sh[k]);
            if (dist < best) { best = dist; bidx = k0 + k; }
        }
    }
    out[IDX_OFF + row] = (float)bidx;
}

__global__ __launch_bounds__(256) void gather_kernel(const float* __restrict__ z,
                                                     const float* __restrict__ cb,
                                                     float* __restrict__ out,
                                                     float* __restrict__ part) {
    const long g4 = (long)blockIdx.x * 256 + threadIdx.x;
    const long g  = g4 * 4;
    const int  r  = (int)(g >> 6);
    const int  d  = (int)(g & 63);
    const int k = (int)out[IDX_OFF + r];
    float4 zv = reinterpret_cast<const float4*>(z)[g4];
    float4 cv = reinterpret_cast<const float4*>(cb)[(long)k * 16 + (d >> 2)];
    float4 st;
    st.x = zv.x + (cv.x - zv.x); st.y = zv.y + (cv.y - zv.y);
    st.z = zv.z + (cv.z - zv.z); st.w = zv.w + (cv.w - zv.w);
    reinterpret_cast<float4*>(out)[g4] = st;
    float* zq = out + ZQ_OFF + g;
    zq[0] = cv.x; zq[1] = cv.y; zq[2] = cv.z; zq[3] = cv.w;
    float dx = cv.x - zv.x, dy = cv.y - zv.y, dz = cv.z - zv.z, dw = cv.w - zv.w;
    float s = fmaf(dx, dx, fmaf(dy, dy, fmaf(dz, dz, dw * dw)));
    #pragma unroll
    for (int off = 32; off > 0; off >>= 1) s += __shfl_down(s, off, 64);
    __shared__ float wsum[4];
    const int lane = threadIdx.x & 63, wid = threadIdx.x >> 6;
    if (lane == 0) wsum[wid] = s;
    __syncthreads();
    if (threadIdx.x == 0)
        part[blockIdx.x] = (wsum[0] + wsum[1]) + (wsum[2] + wsum[3]);
}

__global__ __launch_bounds__(256) void loss_old_kernel(const float* __restrict__ part,
                                                       float* __restrict__ out) {
    double s = 0.0;
    for (int i = threadIdx.x; i < EPI_BLOCKS; i += 256) s += (double)part[i];
    #pragma unroll
    for (int off = 32; off > 0; off >>= 1) s += __shfl_down(s, off, 64);
    __shared__ double dsum[4];
    const int lane = threadIdx.x & 63, wid = threadIdx.x >> 6;
    if (lane == 0) dsum[wid] = s;
    __syncthreads();
    if (threadIdx.x == 0) {
        double total = (dsum[0] + dsum[1]) + (dsum[2] + dsum[3]);
        out[LOSS_OFF] = (float)(1.25 * (total / (double)((long)N_ROWS * D_DIM)));
    }
}

extern "C" void kernel_launch(void* const* d_in, const int* in_sizes, int n_in,
                              void* d_out, int out_size, void* d_ws, size_t ws_size,
                              hipStream_t stream) {
    (void)in_sizes; (void)n_in; (void)out_size;
    const float* z  = (const float*)d_in[0];
    const float* cb = (const float*)d_in[1];
    float* out = (float*)d_out;
    char*  wsb = (char*)d_ws;
    float* wsf = (float*)d_ws;

    if (ws_size >= WS_NEEDED) {
        fusedprep_kernel<<<32,           256, 0, stream>>>(cb, wsb);
        vq_gemm_kernel  <<<N_ROWS / 256, 256, 0, stream>>>(z, cb, wsb, out);
        rescore_kernel  <<<256,          256, 0, stream>>>(z, cb, wsb, out);
        loss_kernel     <<<1,            256, 0, stream>>>(wsb, out);
    } else {
        csq_kernel       <<<K_CODES / 256, 256, 0, stream>>>(cb, wsf);
        argmin_old_kernel<<<N_ROWS / 256,  256, 0, stream>>>(z, cb, wsf, out);
        gather_kernel    <<<EPI_BLOCKS,    256, 0, stream>>>(z, cb, out, wsf + 1024);
        loss_old_kernel  <<<1,             256, 0, stream>>>(wsf + 1024, out);
    }
}

// Round 7
// 710.905 us; speedup vs baseline: 1.0250x; 1.0250x over previous
//
#include <hip/hip_runtime.h>
#include <hip/hip_bf16.h>

typedef __bf16 bf16x8 __attribute__((ext_vector_type(8)));
typedef float  f32x4  __attribute__((ext_vector_type(4)));

static constexpr int N_ROWS  = 262144;
static constexpr int K_CODES = 1024;
static constexpr int D_DIM   = 64;

// d_out layout (floats): z_q_st[N*D], vq_loss, indices[N], z_q[N*D]
static constexpr long LOSS_OFF = (long)N_ROWS * D_DIM;   // 16777216
static constexpr long IDX_OFF  = LOSS_OFF + 1;           // 16777217
static constexpr long ZQ_OFF   = IDX_OFF + N_ROWS;       // 17039361

// ws byte layout
static constexpr size_t CSQ_B   = 0;                              // f32[1024]
static constexpr size_t BFRAG_B = 4096;                           // 16 tiles * 16 KB
static constexpr size_t CNT_B   = BFRAG_B + (size_t)16 * 16384;   // 266240
static constexpr size_t PART_B  = CNT_B + 256;                    // 266496: f32[16384]
static constexpr size_t LIST_B  = PART_B + (size_t)16384 * 4;     // 332032: int[N]
static constexpr size_t WS_NEEDED = LIST_B + (size_t)N_ROWS * 4;  // ~1.38 MB

static constexpr float MARGIN = 0.05f;
static constexpr int   EPI_BLOCKS = (N_ROWS * D_DIM) / (256 * 4); // 16384
static constexpr int   RESCORE_BLOCKS = 2048;

#define GLOAD_LDS16(g, l) __builtin_amdgcn_global_load_lds( \
    (const __attribute__((address_space(1))) unsigned int*)(g), \
    (__attribute__((address_space(3))) unsigned int*)(l), 16, 0, 0)

// ---------------- fused prep: csq + bf16 hi/lo fragments + cnt zero ----------
__global__ __launch_bounds__(256) void fusedprep_kernel(const float* __restrict__ cb,
                                                        char* __restrict__ wsb) {
    const int t = blockIdx.x * 256 + threadIdx.x;   // 0..8191 = c*8 + ks*4 + g
    if (t == 0) *(int*)(wsb + CNT_B) = 0;

    // csq: EXACT same arithmetic order as rounds 1-4 (argmin consistency)
    if (t < K_CODES) {
        const float4* row = reinterpret_cast<const float4*>(cb) + (size_t)t * (D_DIM / 4);
        float s = 0.f;
        #pragma unroll
        for (int j = 0; j < D_DIM / 4; ++j) {
            float4 v = row[j];
            s = fmaf(v.x, v.x, s); s = fmaf(v.y, v.y, s);
            s = fmaf(v.z, v.z, s); s = fmaf(v.w, v.w, s);
        }
        ((float*)(wsb + CSQ_B))[t] = s;
    }

    // fragment split: B-frag lane l supplies B[k][n], n=l&15, k=32*ks+8*(l>>4)+i
    const int c  = t >> 3;
    const int ks = (t >> 2) & 1;
    const int g  = t & 3;
    const float* src = cb + (size_t)c * 64 + ks * 32 + g * 8;
    float f[8];
    #pragma unroll
    for (int i = 0; i < 8; ++i) f[i] = src[i];
    bf16x8 h, l;
    #pragma unroll
    for (int i = 0; i < 8; ++i) {
        __bf16 hv = (__bf16)f[i];
        h[i] = hv;
        l[i] = (__bf16)(f[i] - (float)hv);
    }
    const int tile = c >> 6, cf = (c >> 4) & 3, n = c & 15;
    const int lane = g * 16 + n;
    char* base = wsb + BFRAG_B + (size_t)tile * 16384;
    *reinterpret_cast<bf16x8*>(base + ((0 * 2 + ks) * 4 + cf) * 1024 + lane * 16) = h;
    *reinterpret_cast<bf16x8*>(base + ((1 * 2 + ks) * 4 + cf) * 1024 + lane * 16) = l;
}

// ---------------- main: MFMA bf16x3 distance argmin (no fused epilogue) ------
__global__ __launch_bounds__(256, 4) void vq_gemm_kernel(const float* __restrict__ z,
                                                         char* __restrict__ wsb,
                                                         float* __restrict__ out) {
    __shared__ __align__(16) unsigned char sbuf[2 * 16384 + 4096];
    float* lds_csq = (float*)(sbuf + 32768);

    const int tid  = threadIdx.x;
    const int lane = tid & 63, wid = tid >> 6;
    const int l15  = lane & 15, lg = lane >> 4;

    const float* csq = (const float*)(wsb + CSQ_B);
    #pragma unroll
    for (int i = 0; i < 4; ++i) lds_csq[tid + 256 * i] = csq[tid + 256 * i];

    // A fragments: lane l supplies A[m][k], m = l&15, k = 32*ks + 8*(l>>4)+i
    const int rowbase = blockIdx.x * 256 + wid * 64;
    bf16x8 ah[4][2], al[4][2];
    #pragma unroll
    for (int rf = 0; rf < 4; ++rf) {
        const float* zr = z + (size_t)(rowbase + rf * 16 + l15) * 64 + lg * 8;
        #pragma unroll
        for (int ks = 0; ks < 2; ++ks) {
            float4 a = *reinterpret_cast<const float4*>(zr + ks * 32);
            float4 b = *reinterpret_cast<const float4*>(zr + ks * 32 + 4);
            float f[8] = {a.x, a.y, a.z, a.w, b.x, b.y, b.z, b.w};
            bf16x8 h, l;
            #pragma unroll
            for (int i = 0; i < 8; ++i) {
                __bf16 hv = (__bf16)f[i];
                h[i] = hv;
                l[i] = (__bf16)(f[i] - (float)hv);
            }
            ah[rf][ks] = h; al[rf][ks] = l;
        }
    }

    float m1[16], m2[16]; int i1[16];
    #pragma unroll
    for (int s = 0; s < 16; ++s) { m1[s] = INFINITY; m2[s] = INFINITY; i1[s] = 0; }

    const char* bsrc = wsb + BFRAG_B;
    auto stage = [&](int buf, int t) {
        const char* src = bsrc + (size_t)t * 16384;
        #pragma unroll
        for (int it = 0; it < 4; ++it) {
            GLOAD_LDS16(src + it * 4096 + wid * 1024 + lane * 16,
                        sbuf + buf * 16384 + it * 4096 + wid * 1024);
        }
    };

    stage(0, 0);
    __syncthreads();

    for (int t = 0; t < 16; ++t) {
        if (t < 15) stage((t + 1) & 1, t + 1);
        const unsigned char* B = sbuf + (t & 1) * 16384;
        #pragma unroll
        for (int cf = 0; cf < 4; ++cf) {
            bf16x8 bh0 = *reinterpret_cast<const bf16x8*>(B + (0 * 4 + cf) * 1024 + lane * 16);
            bf16x8 bh1 = *reinterpret_cast<const bf16x8*>(B + (1 * 4 + cf) * 1024 + lane * 16);
            bf16x8 bl0 = *reinterpret_cast<const bf16x8*>(B + (2 * 4 + cf) * 1024 + lane * 16);
            bf16x8 bl1 = *reinterpret_cast<const bf16x8*>(B + (3 * 4 + cf) * 1024 + lane * 16);
            const int code = t * 64 + cf * 16 + l15;
            const float cq = lds_csq[code];
            #pragma unroll
            for (int rf = 0; rf < 4; ++rf) {
                f32x4 acc = {0.f, 0.f, 0.f, 0.f};
                acc = __builtin_amdgcn_mfma_f32_16x16x32_bf16(ah[rf][0], bh0, acc, 0, 0, 0);
                acc = __builtin_amdgcn_mfma_f32_16x16x32_bf16(ah[rf][1], bh1, acc, 0, 0, 0);
                acc = __builtin_amdgcn_mfma_f32_16x16x32_bf16(al[rf][0], bh0, acc, 0, 0, 0);
                acc = __builtin_amdgcn_mfma_f32_16x16x32_bf16(al[rf][1], bh1, acc, 0, 0, 0);
                acc = __builtin_amdgcn_mfma_f32_16x16x32_bf16(ah[rf][0], bl0, acc, 0, 0, 0);
                acc = __builtin_amdgcn_mfma_f32_16x16x32_bf16(ah[rf][1], bl1, acc, 0, 0, 0);
                #pragma unroll
                for (int r = 0; r < 4; ++r) {
                    float dist = fmaf(-2.f, acc[r], cq);
                    int s = rf * 4 + r;
                    bool lt = dist < m1[s];
                    m2[s] = fminf(m2[s], fmaxf(dist, m1[s]));
                    m1[s] = fminf(m1[s], dist);
                    i1[s] = lt ? code : i1[s];
                }
            }
        }
        __syncthreads();
    }

    // merge across the 16 lanes of each lane-group
    #pragma unroll
    for (int s = 0; s < 16; ++s) {
        #pragma unroll
        for (int off = 1; off < 16; off <<= 1) {
            float om1 = __shfl_xor(m1[s], off);
            float om2 = __shfl_xor(m2[s], off);
            int   oi  = __shfl_xor(i1[s], off);
            bool lt = (om1 < m1[s]) || (om1 == m1[s] && oi < i1[s]);
            m2[s] = fminf(fminf(m2[s], om2), fmaxf(m1[s], om1));
            m1[s] = fminf(m1[s], om1);
            i1[s] = lt ? oi : i1[s];
        }
    }

    if (l15 == 0) {
        int* cnt  = (int*)(wsb + CNT_B);
        int* list = (int*)(wsb + LIST_B);
        #pragma unroll
        for (int rf = 0; rf < 4; ++rf) {
            #pragma unroll
            for (int r = 0; r < 4; ++r) {
                int s = rf * 4 + r;
                int row = rowbase + rf * 16 + lg * 4 + r;
                out[IDX_OFF + row] = (float)i1[s];
                if (m2[s] - m1[s] < MARGIN) {
                    int pos = atomicAdd(cnt, 1);
                    if (pos < N_ROWS) list[pos] = row;
                }
            }
        }
    }
}

// ---------------- exact fp32 re-argmin for flagged rows (idx fix only) ------
__global__ __launch_bounds__(256) void rescore_kernel(const float* __restrict__ z,
                                                      const float* __restrict__ cb,
                                                      const char* __restrict__ wsb,
                                                      float* __restrict__ out) {
    const int lane = threadIdx.x & 63;
    const int wgid = (blockIdx.x * 256 + threadIdx.x) >> 6;
    int cnt = *(const int*)(wsb + CNT_B);
    if (cnt > N_ROWS) cnt = N_ROWS;
    const int*   list = (const int*)(wsb + LIST_B);
    const float* csq  = (const float*)(wsb + CSQ_B);

    for (int i = wgid; i < cnt; i += RESCORE_BLOCKS * 4) {
        const int row = list[i];
        float4 zr[16];
        const float4* zp = reinterpret_cast<const float4*>(z) + (size_t)row * 16;
        #pragma unroll
        for (int j = 0; j < 16; ++j) zr[j] = zp[j];
        float best = INFINITY; int bi = 0;
        for (int k = lane; k < K_CODES; k += 64) {
            const float4* cp = reinterpret_cast<const float4*>(cb) + (size_t)k * 16;
            float d0 = 0.f, d1 = 0.f, d2 = 0.f, d3 = 0.f;
            #pragma unroll
            for (int j = 0; j < 16; j += 4) {
                float4 c0 = cp[j + 0], c1 = cp[j + 1], c2 = cp[j + 2], c3 = cp[j + 3];
                d0 = fmaf(zr[j+0].x, c0.x, fmaf(zr[j+0].y, c0.y, fmaf(zr[j+0].z, c0.z, fmaf(zr[j+0].w, c0.w, d0))));
                d1 = fmaf(zr[j+1].x, c1.x, fmaf(zr[j+1].y, c1.y, fmaf(zr[j+1].z, c1.z, fmaf(zr[j+1].w, c1.w, d1))));
                d2 = fmaf(zr[j+2].x, c2.x, fmaf(zr[j+2].y, c2.y, fmaf(zr[j+2].z, c2.z, fmaf(zr[j+2].w, c2.w, d2))));
                d3 = fmaf(zr[j+3].x, c3.x, fmaf(zr[j+3].y, c3.y, fmaf(zr[j+3].z, c3.z, fmaf(zr[j+3].w, c3.w, d3))));
            }
            float dist = fmaf(-2.f, (d0 + d1) + (d2 + d3), csq[k]);
            if (dist < best) { best = dist; bi = k; }
        }
        #pragma unroll
        for (int off = 1; off < 64; off <<= 1) {
            float ob = __shfl_xor(best, off);
            int   oi = __shfl_xor(bi, off);
            if (ob < best || (ob == best && oi < bi)) { best = ob; bi = oi; }
        }
        if (lane == 0) out[IDX_OFF + row] = (float)bi;
    }
}

// ---------------- streaming gather epilogue (round-3 proven) ----------------
__global__ __launch_bounds__(256) void gather_kernel(const float* __restrict__ z,
                                                     const float* __restrict__ cb,
                                                     float* __restrict__ out,
                                                     float* __restrict__ part) {
    const long g4 = (long)blockIdx.x * 256 + threadIdx.x;
    const long g  = g4 * 4;
    const int  r  = (int)(g >> 6);
    const int  d  = (int)(g & 63);
    const int k = (int)out[IDX_OFF + r];
    float4 zv = reinterpret_cast<const float4*>(z)[g4];
    float4 cv = reinterpret_cast<const float4*>(cb)[(long)k * 16 + (d >> 2)];
    float4 st;
    st.x = zv.x + (cv.x - zv.x); st.y = zv.y + (cv.y - zv.y);
    st.z = zv.z + (cv.z - zv.z); st.w = zv.w + (cv.w - zv.w);
    reinterpret_cast<float4*>(out)[g4] = st;
    float* zq = out + ZQ_OFF + g;
    zq[0] = cv.x; zq[1] = cv.y; zq[2] = cv.z; zq[3] = cv.w;
    float dx = cv.x - zv.x, dy = cv.y - zv.y, dz = cv.z - zv.z, dw = cv.w - zv.w;
    float s = fmaf(dx, dx, fmaf(dy, dy, fmaf(dz, dz, dw * dw)));
    #pragma unroll
    for (int off = 32; off > 0; off >>= 1) s += __shfl_down(s, off, 64);
    __shared__ float wsum[4];
    const int lane = threadIdx.x & 63, wid = threadIdx.x >> 6;
    if (lane == 0) wsum[wid] = s;
    __syncthreads();
    if (threadIdx.x == 0)
        part[blockIdx.x] = (wsum[0] + wsum[1]) + (wsum[2] + wsum[3]);
}

__global__ __launch_bounds__(256) void loss_kernel(const float* __restrict__ part,
                                                   float* __restrict__ out) {
    double s = 0.0;
    for (int i = threadIdx.x; i < EPI_BLOCKS; i += 256) s += (double)part[i];
    #pragma unroll
    for (int off = 32; off > 0; off >>= 1) s += __shfl_down(s, off, 64);
    __shared__ double dsum[4];
    const int lane = threadIdx.x & 63, wid = threadIdx.x >> 6;
    if (lane == 0) dsum[wid] = s;
    __syncthreads();
    if (threadIdx.x == 0) {
        double total = (dsum[0] + dsum[1]) + (dsum[2] + dsum[3]);
        out[LOSS_OFF] = (float)(1.25 * (total / (double)((long)N_ROWS * D_DIM)));
    }
}

// ---------------- fallback path (round-1, known-good) ------------------------
__global__ __launch_bounds__(256) void csq_kernel(const float* __restrict__ cb,
                                                  float* __restrict__ ws) {
    int g = blockIdx.x * 256 + threadIdx.x;
    const float4* row = reinterpret_cast<const float4*>(cb) + (size_t)g * (D_DIM / 4);
    float s = 0.f;
    #pragma unroll
    for (int j = 0; j < D_DIM / 4; ++j) {
        float4 v = row[j];
        s = fmaf(v.x, v.x, s); s = fmaf(v.y, v.y, s);
        s = fmaf(v.z, v.z, s); s = fmaf(v.w, v.w, s);
    }
    ws[g] = s;
}

__global__ __launch_bounds__(256) void argmin_old_kernel(const float* __restrict__ z,
                                                         const float* __restrict__ cb,
                                                         const float* __restrict__ ws,
                                                         float* __restrict__ out) {
    __shared__ float4 tile[64 * 16];
    __shared__ float  csq_sh[64];
    const int row = blockIdx.x * 256 + threadIdx.x;
    float4 zr[16];
    const float4* zp = reinterpret_cast<const float4*>(z) + (size_t)row * 16;
    #pragma unroll
    for (int j = 0; j < 16; ++j) zr[j] = zp[j];
    float best = __builtin_inff();
    int   bidx = 0;
    for (int k0 = 0; k0 < K_CODES; k0 += 64) {
        __syncthreads();
        const float4* src = reinterpret_cast<const float4*>(cb) + (size_t)k0 * 16;
        #pragma unroll
        for (int j = 0; j < 4; ++j)
            tile[threadIdx.x + 256 * j] = src[threadIdx.x + 256 * j];
        if (threadIdx.x < 64) csq_sh[threadIdx.x] = ws[k0 + threadIdx.x];
        __syncthreads();
        #pragma unroll 2
        for (int k = 0; k < 64; ++k) {
            float d0 = 0.f, d1 = 0.f, d2 = 0.f, d3 = 0.f;
            #pragma unroll
            for (int j = 0; j < 16; j += 4) {
                float4 c0 = tile[k*16+j+0], c1 = tile[k*16+j+1], c2 = tile[k*16+j+2], c3 = tile[k*16+j+3];
                d0 = fmaf(zr[j+0].x, c0.x, fmaf(zr[j+0].y, c0.y, fmaf(zr[j+0].z, c0.z, fmaf(zr[j+0].w, c0.w, d0))));
                d1 = fmaf(zr[j+1].x, c1.x, fmaf(zr[j+1].y, c1.y, fmaf(zr[j+1].z, c1.z, fmaf(zr[j+1].w, c1.w, d1))));
                d2 = fmaf(zr[j+2].x, c2.x, fmaf(zr[j+2].y, c2.y, fmaf(zr[j+2].z, c2.z, fmaf(zr[j+2].w, c2.w, d2))));
                d3 = fmaf(zr[j+3].x, c3.x, fmaf(zr[j+3].y, c3.y, fmaf(zr[j+3].z, c3.z, fmaf(zr[j+3].w, c3.w, d3))));
            }
            float dist = fmaf(-2.f, (d0 + d1) + (d2 + d3), csq_sh[k]);
            if (dist < best) { best = dist; bidx = k0 + k; }
        }
    }
    out[IDX_OFF + row] = (float)bidx;
}

extern "C" void kernel_launch(void* const* d_in, const int* in_sizes, int n_in,
                              void* d_out, int out_size, void* d_ws, size_t ws_size,
                              hipStream_t stream) {
    (void)in_sizes; (void)n_in; (void)out_size;
    const float* z  = (const float*)d_in[0];
    const float* cb = (const float*)d_in[1];
    float* out = (float*)d_out;
    char*  wsb = (char*)d_ws;
    float* wsf = (float*)d_ws;

    if (ws_size >= WS_NEEDED) {
        fusedprep_kernel<<<32,             256, 0, stream>>>(cb, wsb);
        vq_gemm_kernel  <<<N_ROWS / 256,   256, 0, stream>>>(z, wsb, out);
        rescore_kernel  <<<RESCORE_BLOCKS, 256, 0, stream>>>(z, cb, wsb, out);
        gather_kernel   <<<EPI_BLOCKS,     256, 0, stream>>>(z, cb, out, (float*)(wsb + PART_B));
        loss_kernel     <<<1,              256, 0, stream>>>((const float*)(wsb + PART_B), out);
    } else {
        csq_kernel       <<<K_CODES / 256, 256, 0, stream>>>(cb, wsf);
        argmin_old_kernel<<<N_ROWS / 256,  256, 0, stream>>>(z, cb, wsf, out);
        gather_kernel    <<<EPI_BLOCKS,    256, 0, stream>>>(z, cb, out, wsf + 1024);
        loss_kernel      <<<1,             256, 0, stream>>>(wsf + 1024, out);
    }
}

// Round 8
// 396.010 us; speedup vs baseline: 1.8400x; 1.7952x over previous
//
#include <hip/hip_runtime.h>
#include <hip/hip_bf16.h>

typedef __bf16 bf16x8 __attribute__((ext_vector_type(8)));
typedef float  f32x4  __attribute__((ext_vector_type(4)));

static constexpr int N_ROWS  = 262144;
static constexpr int K_CODES = 1024;
static constexpr int D_DIM   = 64;

// d_out layout (floats): z_q_st[N*D], vq_loss, indices[N], z_q[N*D]
static constexpr long LOSS_OFF = (long)N_ROWS * D_DIM;   // 16777216
static constexpr long IDX_OFF  = LOSS_OFF + 1;           // 16777217
static constexpr long ZQ_OFF   = IDX_OFF + N_ROWS;       // 17039361

// ws byte layout
static constexpr size_t CSQ_B   = 0;                              // f32[1024]
static constexpr size_t BFRAG_B = 4096;                           // 16 tiles * 16 KB
static constexpr size_t CNT_B   = BFRAG_B + (size_t)16 * 16384;   // 266240
static constexpr size_t PART_B  = CNT_B + 256;                    // 266496: f32[16384]
static constexpr size_t LIST_B  = PART_B + (size_t)16384 * 4;     // 332032: int[N]
static constexpr size_t WS_NEEDED = LIST_B + (size_t)N_ROWS * 4;  // ~1.38 MB

static constexpr float MARGIN = 0.05f;
static constexpr int   EPI_BLOCKS = (N_ROWS * D_DIM) / (256 * 4); // 16384
static constexpr int   RESCORE_BLOCKS = 2048;

#define GLOAD_LDS16(g, l) __builtin_amdgcn_global_load_lds( \
    (const __attribute__((address_space(1))) unsigned int*)(g), \
    (__attribute__((address_space(3))) unsigned int*)(l), 16, 0, 0)

// ---------------- fused prep: csq + bf16 hi/lo fragments + cnt zero ----------
__global__ __launch_bounds__(256) void fusedprep_kernel(const float* __restrict__ cb,
                                                        char* __restrict__ wsb) {
    const int t = blockIdx.x * 256 + threadIdx.x;   // 0..8191 = c*8 + ks*4 + g
    if (t == 0) *(int*)(wsb + CNT_B) = 0;

    // csq: EXACT same arithmetic order as rounds 1-7 (argmin consistency)
    if (t < K_CODES) {
        const float4* row = reinterpret_cast<const float4*>(cb) + (size_t)t * (D_DIM / 4);
        float s = 0.f;
        #pragma unroll
        for (int j = 0; j < D_DIM / 4; ++j) {
            float4 v = row[j];
            s = fmaf(v.x, v.x, s); s = fmaf(v.y, v.y, s);
            s = fmaf(v.z, v.z, s); s = fmaf(v.w, v.w, s);
        }
        ((float*)(wsb + CSQ_B))[t] = s;
    }

    // fragment split: B-frag lane l supplies B[k][n], n=l&15, k=32*ks+8*(l>>4)+i
    const int c  = t >> 3;
    const int ks = (t >> 2) & 1;
    const int g  = t & 3;
    const float* src = cb + (size_t)c * 64 + ks * 32 + g * 8;
    float f[8];
    #pragma unroll
    for (int i = 0; i < 8; ++i) f[i] = src[i];
    bf16x8 h, l;
    #pragma unroll
    for (int i = 0; i < 8; ++i) {
        __bf16 hv = (__bf16)f[i];
        h[i] = hv;
        l[i] = (__bf16)(f[i] - (float)hv);
    }
    const int tile = c >> 6, cf = (c >> 4) & 3, n = c & 15;
    const int lane = g * 16 + n;
    char* base = wsb + BFRAG_B + (size_t)tile * 16384;
    *reinterpret_cast<bf16x8*>(base + ((0 * 2 + ks) * 4 + cf) * 1024 + lane * 16) = h;
    *reinterpret_cast<bf16x8*>(base + ((1 * 2 + ks) * 4 + cf) * 1024 + lane * 16) = l;
}

// ---------------- main: MFMA bf16x3 distance argmin --------------------------
// launch_bounds(256, 2): (256,4) capped unified VGPR+AGPR at ~128 -> compiler
// spilled frag/min arrays to scratch (r4/r7: 1.9 GB HBM spill traffic, 456 us).
// At (256,2) the kernel fits (VGPR 112 + AGPRs) with zero spill (r3: 130 us).
__global__ __launch_bounds__(256, 2) void vq_gemm_kernel(const float* __restrict__ z,
                                                         char* __restrict__ wsb,
                                                         float* __restrict__ out) {
    __shared__ __align__(16) unsigned char sbuf[2 * 16384 + 4096];
    float* lds_csq = (float*)(sbuf + 32768);

    const int tid  = threadIdx.x;
    const int lane = tid & 63, wid = tid >> 6;
    const int l15  = lane & 15, lg = lane >> 4;

    const float* csq = (const float*)(wsb + CSQ_B);
    #pragma unroll
    for (int i = 0; i < 4; ++i) lds_csq[tid + 256 * i] = csq[tid + 256 * i];

    // A fragments: lane l supplies A[m][k], m = l&15, k = 32*ks + 8*(l>>4)+i
    const int rowbase = blockIdx.x * 256 + wid * 64;
    bf16x8 ah[4][2], al[4][2];
    #pragma unroll
    for (int rf = 0; rf < 4; ++rf) {
        const float* zr = z + (size_t)(rowbase + rf * 16 + l15) * 64 + lg * 8;
        #pragma unroll
        for (int ks = 0; ks < 2; ++ks) {
            float4 a = *reinterpret_cast<const float4*>(zr + ks * 32);
            float4 b = *reinterpret_cast<const float4*>(zr + ks * 32 + 4);
            float f[8] = {a.x, a.y, a.z, a.w, b.x, b.y, b.z, b.w};
            bf16x8 h, l;
            #pragma unroll
            for (int i = 0; i < 8; ++i) {
                __bf16 hv = (__bf16)f[i];
                h[i] = hv;
                l[i] = (__bf16)(f[i] - (float)hv);
            }
            ah[rf][ks] = h; al[rf][ks] = l;
        }
    }

    float m1[16], m2[16]; int i1[16];
    #pragma unroll
    for (int s = 0; s < 16; ++s) { m1[s] = INFINITY; m2[s] = INFINITY; i1[s] = 0; }

    const char* bsrc = wsb + BFRAG_B;
    auto stage = [&](int buf, int t) {
        const char* src = bsrc + (size_t)t * 16384;
        #pragma unroll
        for (int it = 0; it < 4; ++it) {
            GLOAD_LDS16(src + it * 4096 + wid * 1024 + lane * 16,
                        sbuf + buf * 16384 + it * 4096 + wid * 1024);
        }
    };

    stage(0, 0);
    __syncthreads();

    for (int t = 0; t < 16; ++t) {
        if (t < 15) stage((t + 1) & 1, t + 1);
        const unsigned char* B = sbuf + (t & 1) * 16384;
        #pragma unroll
        for (int cf = 0; cf < 4; ++cf) {
            bf16x8 bh0 = *reinterpret_cast<const bf16x8*>(B + (0 * 4 + cf) * 1024 + lane * 16);
            bf16x8 bh1 = *reinterpret_cast<const bf16x8*>(B + (1 * 4 + cf) * 1024 + lane * 16);
            bf16x8 bl0 = *reinterpret_cast<const bf16x8*>(B + (2 * 4 + cf) * 1024 + lane * 16);
            bf16x8 bl1 = *reinterpret_cast<const bf16x8*>(B + (3 * 4 + cf) * 1024 + lane * 16);
            const int code = t * 64 + cf * 16 + l15;
            const float cq = lds_csq[code];
            #pragma unroll
            for (int rf = 0; rf < 4; ++rf) {
                f32x4 acc = {0.f, 0.f, 0.f, 0.f};
                acc = __builtin_amdgcn_mfma_f32_16x16x32_bf16(ah[rf][0], bh0, acc, 0, 0, 0);
                acc = __builtin_amdgcn_mfma_f32_16x16x32_bf16(ah[rf][1], bh1, acc, 0, 0, 0);
                acc = __builtin_amdgcn_mfma_f32_16x16x32_bf16(al[rf][0], bh0, acc, 0, 0, 0);
                acc = __builtin_amdgcn_mfma_f32_16x16x32_bf16(al[rf][1], bh1, acc, 0, 0, 0);
                acc = __builtin_amdgcn_mfma_f32_16x16x32_bf16(ah[rf][0], bl0, acc, 0, 0, 0);
                acc = __builtin_amdgcn_mfma_f32_16x16x32_bf16(ah[rf][1], bl1, acc, 0, 0, 0);
                #pragma unroll
                for (int r = 0; r < 4; ++r) {
                    float dist = fmaf(-2.f, acc[r], cq);
                    int s = rf * 4 + r;
                    bool lt = dist < m1[s];
                    m2[s] = fminf(m2[s], fmaxf(dist, m1[s]));
                    m1[s] = fminf(m1[s], dist);
                    i1[s] = lt ? code : i1[s];
                }
            }
        }
        __syncthreads();
    }

    // merge across the 16 lanes of each lane-group
    #pragma unroll
    for (int s = 0; s < 16; ++s) {
        #pragma unroll
        for (int off = 1; off < 16; off <<= 1) {
            float om1 = __shfl_xor(m1[s], off);
            float om2 = __shfl_xor(m2[s], off);
            int   oi  = __shfl_xor(i1[s], off);
            bool lt = (om1 < m1[s]) || (om1 == m1[s] && oi < i1[s]);
            m2[s] = fminf(fminf(m2[s], om2), fmaxf(m1[s], om1));
            m1[s] = fminf(m1[s], om1);
            i1[s] = lt ? oi : i1[s];
        }
    }

    if (l15 == 0) {
        int* cnt  = (int*)(wsb + CNT_B);
        int* list = (int*)(wsb + LIST_B);
        #pragma unroll
        for (int rf = 0; rf < 4; ++rf) {
            #pragma unroll
            for (int r = 0; r < 4; ++r) {
                int s = rf * 4 + r;
                int row = rowbase + rf * 16 + lg * 4 + r;
                out[IDX_OFF + row] = (float)i1[s];
                if (m2[s] - m1[s] < MARGIN) {
                    int pos = atomicAdd(cnt, 1);
                    if (pos < N_ROWS) list[pos] = row;
                }
            }
        }
    }
}

// ---------------- exact fp32 re-argmin for flagged rows (idx fix only) ------
__global__ __launch_bounds__(256) void rescore_kernel(const float* __restrict__ z,
                                                      const float* __restrict__ cb,
                                                      const char* __restrict__ wsb,
                                                      float* __restrict__ out) {
    const int lane = threadIdx.x & 63;
    const int wgid = (blockIdx.x * 256 + threadIdx.x) >> 6;
    int cnt = *(const int*)(wsb + CNT_B);
    if (cnt > N_ROWS) cnt = N_ROWS;
    const int*   list = (const int*)(wsb + LIST_B);
    const float* csq  = (const float*)(wsb + CSQ_B);

    for (int i = wgid; i < cnt; i += RESCORE_BLOCKS * 4) {
        const int row = list[i];
        float4 zr[16];
        const float4* zp = reinterpret_cast<const float4*>(z) + (size_t)row * 16;
        #pragma unroll
        for (int j = 0; j < 16; ++j) zr[j] = zp[j];
        float best = INFINITY; int bi = 0;
        for (int k = lane; k < K_CODES; k += 64) {
            const float4* cp = reinterpret_cast<const float4*>(cb) + (size_t)k * 16;
            float d0 = 0.f, d1 = 0.f, d2 = 0.f, d3 = 0.f;
            #pragma unroll
            for (int j = 0; j < 16; j += 4) {
                float4 c0 = cp[j + 0], c1 = cp[j + 1], c2 = cp[j + 2], c3 = cp[j + 3];
                d0 = fmaf(zr[j+0].x, c0.x, fmaf(zr[j+0].y, c0.y, fmaf(zr[j+0].z, c0.z, fmaf(zr[j+0].w, c0.w, d0))));
                d1 = fmaf(zr[j+1].x, c1.x, fmaf(zr[j+1].y, c1.y, fmaf(zr[j+1].z, c1.z, fmaf(zr[j+1].w, c1.w, d1))));
                d2 = fmaf(zr[j+2].x, c2.x, fmaf(zr[j+2].y, c2.y, fmaf(zr[j+2].z, c2.z, fmaf(zr[j+2].w, c2.w, d2))));
                d3 = fmaf(zr[j+3].x, c3.x, fmaf(zr[j+3].y, c3.y, fmaf(zr[j+3].z, c3.z, fmaf(zr[j+3].w, c3.w, d3))));
            }
            float dist = fmaf(-2.f, (d0 + d1) + (d2 + d3), csq[k]);
            if (dist < best) { best = dist; bi = k; }
        }
        #pragma unroll
        for (int off = 1; off < 64; off <<= 1) {
            float ob = __shfl_xor(best, off);
            int   oi = __shfl_xor(bi, off);
            if (ob < best || (ob == best && oi < bi)) { best = ob; bi = oi; }
        }
        if (lane == 0) out[IDX_OFF + row] = (float)bi;
    }
}

// ---------------- streaming gather epilogue (round-3 proven) ----------------
__global__ __launch_bounds__(256) void gather_kernel(const float* __restrict__ z,
                                                     const float* __restrict__ cb,
                                                     float* __restrict__ out,
                                                     float* __restrict__ part) {
    const long g4 = (long)blockIdx.x * 256 + threadIdx.x;
    const long g  = g4 * 4;
    const int  r  = (int)(g >> 6);
    const int  d  = (int)(g & 63);
    const int k = (int)out[IDX_OFF + r];
    float4 zv = reinterpret_cast<const float4*>(z)[g4];
    float4 cv = reinterpret_cast<const float4*>(cb)[(long)k * 16 + (d >> 2)];
    float4 st;
    st.x = zv.x + (cv.x - zv.x); st.y = zv.y + (cv.y - zv.y);
    st.z = zv.z + (cv.z - zv.z); st.w = zv.w + (cv.w - zv.w);
    reinterpret_cast<float4*>(out)[g4] = st;
    float* zq = out + ZQ_OFF + g;
    zq[0] = cv.x; zq[1] = cv.y; zq[2] = cv.z; zq[3] = cv.w;
    float dx = cv.x - zv.x, dy = cv.y - zv.y, dz = cv.z - zv.z, dw = cv.w - zv.w;
    float s = fmaf(dx, dx, fmaf(dy, dy, fmaf(dz, dz, dw * dw)));
    #pragma unroll
    for (int off = 32; off > 0; off >>= 1) s += __shfl_down(s, off, 64);
    __shared__ float wsum[4];
    const int lane = threadIdx.x & 63, wid = threadIdx.x >> 6;
    if (lane == 0) wsum[wid] = s;
    __syncthreads();
    if (threadIdx.x == 0)
        part[blockIdx.x] = (wsum[0] + wsum[1]) + (wsum[2] + wsum[3]);
}

__global__ __launch_bounds__(256) void loss_kernel(const float* __restrict__ part,
                                                   float* __restrict__ out) {
    double s = 0.0;
    for (int i = threadIdx.x; i < EPI_BLOCKS; i += 256) s += (double)part[i];
    #pragma unroll
    for (int off = 32; off > 0; off >>= 1) s += __shfl_down(s, off, 64);
    __shared__ double dsum[4];
    const int lane = threadIdx.x & 63, wid = threadIdx.x >> 6;
    if (lane == 0) dsum[wid] = s;
    __syncthreads();
    if (threadIdx.x == 0) {
        double total = (dsum[0] + dsum[1]) + (dsum[2] + dsum[3]);
        out[LOSS_OFF] = (float)(1.25 * (total / (double)((long)N_ROWS * D_DIM)));
    }
}

// ---------------- fallback path (round-1, known-good) ------------------------
__global__ __launch_bounds__(256) void csq_kernel(const float* __restrict__ cb,
                                                  float* __restrict__ ws) {
    int g = blockIdx.x * 256 + threadIdx.x;
    const float4* row = reinterpret_cast<const float4*>(cb) + (size_t)g * (D_DIM / 4);
    float s = 0.f;
    #pragma unroll
    for (int j = 0; j < D_DIM / 4; ++j) {
        float4 v = row[j];
        s = fmaf(v.x, v.x, s); s = fmaf(v.y, v.y, s);
        s = fmaf(v.z, v.z, s); s = fmaf(v.w, v.w, s);
    }
    ws[g] = s;
}

__global__ __launch_bounds__(256) void argmin_old_kernel(const float* __restrict__ z,
                                                         const float* __restrict__ cb,
                                                         const float* __restrict__ ws,
                                                         float* __restrict__ out) {
    __shared__ float4 tile[64 * 16];
    __shared__ float  csq_sh[64];
    const int row = blockIdx.x * 256 + threadIdx.x;
    float4 zr[16];
    const float4* zp = reinterpret_cast<const float4*>(z) + (size_t)row * 16;
    #pragma unroll
    for (int j = 0; j < 16; ++j) zr[j] = zp[j];
    float best = __builtin_inff();
    int   bidx = 0;
    for (int k0 = 0; k0 < K_CODES; k0 += 64) {
        __syncthreads();
        const float4* src = reinterpret_cast<const float4*>(cb) + (size_t)k0 * 16;
        #pragma unroll
        for (int j = 0; j < 4; ++j)
            tile[threadIdx.x + 256 * j] = src[threadIdx.x + 256 * j];
        if (threadIdx.x < 64) csq_sh[threadIdx.x] = ws[k0 + threadIdx.x];
        __syncthreads();
        #pragma unroll 2
        for (int k = 0; k < 64; ++k) {
            float d0 = 0.f, d1 = 0.f, d2 = 0.f, d3 = 0.f;
            #pragma unroll
            for (int j = 0; j < 16; j += 4) {
                float4 c0 = tile[k*16+j+0], c1 = tile[k*16+j+1], c2 = tile[k*16+j+2], c3 = tile[k*16+j+3];
                d0 = fmaf(zr[j+0].x, c0.x, fmaf(zr[j+0].y, c0.y, fmaf(zr[j+0].z, c0.z, fmaf(zr[j+0].w, c0.w, d0))));
                d1 = fmaf(zr[j+1].x, c1.x, fmaf(zr[j+1].y, c1.y, fmaf(zr[j+1].z, c1.z, fmaf(zr[j+1].w, c1.w, d1))));
                d2 = fmaf(zr[j+2].x, c2.x, fmaf(zr[j+2].y, c2.y, fmaf(zr[j+2].z, c2.z, fmaf(zr[j+2].w, c2.w, d2))));
                d3 = fmaf(zr[j+3].x, c3.x, fmaf(zr[j+3].y, c3.y, fmaf(zr[j+3].z, c3.z, fmaf(zr[j+3].w, c3.w, d3))));
            }
            float dist = fmaf(-2.f, (d0 + d1) + (d2 + d3), csq_sh[k]);
            if (dist < best) { best = dist; bidx = k0 + k; }
        }
    }
    out[IDX_OFF + row] = (float)bidx;
}

extern "C" void kernel_launch(void* const* d_in, const int* in_sizes, int n_in,
                              void* d_out, int out_size, void* d_ws, size_t ws_size,
                              hipStream_t stream) {
    (void)in_sizes; (void)n_in; (void)out_size;
    const float* z  = (const float*)d_in[0];
    const float* cb = (const float*)d_in[1];
    float* out = (float*)d_out;
    char*  wsb = (char*)d_ws;
    float* wsf = (float*)d_ws;

    if (ws_size >= WS_NEEDED) {
        fusedprep_kernel<<<32,             256, 0, stream>>>(cb, wsb);
        vq_gemm_kernel  <<<N_ROWS / 256,   256, 0, stream>>>(z, wsb, out);
        rescore_kernel  <<<RESCORE_BLOCKS, 256, 0, stream>>>(z, cb, wsb, out);
        gather_kernel   <<<EPI_BLOCKS,     256, 0, stream>>>(z, cb, out, (float*)(wsb + PART_B));
        loss_kernel     <<<1,              256, 0, stream>>>((const float*)(wsb + PART_B), out);
    } else {
        csq_kernel       <<<K_CODES / 256, 256, 0, stream>>>(cb, wsf);
        argmin_old_kernel<<<N_ROWS / 256,  256, 0, stream>>>(z, cb, wsf, out);
        gather_kernel    <<<EPI_BLOCKS,    256, 0, stream>>>(z, cb, out, wsf + 1024);
        loss_kernel      <<<1,             256, 0, stream>>>(wsf + 1024, out);
    }
}

// Round 9
// 395.518 us; speedup vs baseline: 1.8423x; 1.0012x over previous
//
#include <hip/hip_runtime.h>
#include <hip/hip_bf16.h>

typedef __bf16 bf16x8 __attribute__((ext_vector_type(8)));
typedef float  f32x4  __attribute__((ext_vector_type(4)));

static constexpr int N_ROWS  = 262144;
static constexpr int K_CODES = 1024;
static constexpr int D_DIM   = 64;

// d_out layout (floats): z_q_st[N*D], vq_loss, indices[N], z_q[N*D]
static constexpr long LOSS_OFF = (long)N_ROWS * D_DIM;   // 16777216
static constexpr long IDX_OFF  = LOSS_OFF + 1;           // 16777217
static constexpr long ZQ_OFF   = IDX_OFF + N_ROWS;       // 17039361

// ws byte layout
static constexpr size_t CSQ_B   = 0;                              // f32[1024]
static constexpr size_t BFRAG_B = 4096;                           // 16 tiles * 16 KB
static constexpr size_t CNT_B   = BFRAG_B + (size_t)16 * 16384;   // 266240
static constexpr size_t PART_B  = CNT_B + 256;                    // 266496: f32[16384]
static constexpr size_t LIST_B  = PART_B + (size_t)16384 * 4;     // 332032: int[N]
static constexpr size_t WS_NEEDED = LIST_B + (size_t)N_ROWS * 4;  // ~1.38 MB

static constexpr float MARGIN = 0.05f;
static constexpr int   EPI_BLOCKS = (N_ROWS * D_DIM) / (256 * 4); // 16384
static constexpr int   RESCORE_BLOCKS = 512;

#define GLOAD_LDS16(g, l) __builtin_amdgcn_global_load_lds( \
    (const __attribute__((address_space(1))) unsigned int*)(g), \
    (__attribute__((address_space(3))) unsigned int*)(l), 16, 0, 0)

// ---------------- fused prep: csq + bf16 hi/lo of (-2*c) + cnt zero ----------
// B fragments pre-scaled by -2 so the MFMA (with C-in = c_sq) directly yields
// dist = c_sq - 2*z.c  -> deletes the per-distance fmaf in the hot loop.
__global__ __launch_bounds__(256) void fusedprep_kernel(const float* __restrict__ cb,
                                                        char* __restrict__ wsb) {
    const int t = blockIdx.x * 256 + threadIdx.x;   // 0..8191 = c*8 + ks*4 + g
    if (t == 0) *(int*)(wsb + CNT_B) = 0;

    // csq: EXACT same arithmetic order as rounds 1-8 (argmin consistency)
    if (t < K_CODES) {
        const float4* row = reinterpret_cast<const float4*>(cb) + (size_t)t * (D_DIM / 4);
        float s = 0.f;
        #pragma unroll
        for (int j = 0; j < D_DIM / 4; ++j) {
            float4 v = row[j];
            s = fmaf(v.x, v.x, s); s = fmaf(v.y, v.y, s);
            s = fmaf(v.z, v.z, s); s = fmaf(v.w, v.w, s);
        }
        ((float*)(wsb + CSQ_B))[t] = s;
    }

    // fragment split of (-2c): B-frag lane l supplies B[k][n], n=l&15, k=32*ks+8*(l>>4)+i
    const int c  = t >> 3;
    const int ks = (t >> 2) & 1;
    const int g  = t & 3;
    const float* src = cb + (size_t)c * 64 + ks * 32 + g * 8;
    float f[8];
    #pragma unroll
    for (int i = 0; i < 8; ++i) f[i] = -2.0f * src[i];
    bf16x8 h, l;
    #pragma unroll
    for (int i = 0; i < 8; ++i) {
        __bf16 hv = (__bf16)f[i];
        h[i] = hv;
        l[i] = (__bf16)(f[i] - (float)hv);
    }
    const int tile = c >> 6, cf = (c >> 4) & 3, n = c & 15;
    const int lane = g * 16 + n;
    char* base = wsb + BFRAG_B + (size_t)tile * 16384;
    *reinterpret_cast<bf16x8*>(base + ((0 * 2 + ks) * 4 + cf) * 1024 + lane * 16) = h;
    *reinterpret_cast<bf16x8*>(base + ((1 * 2 + ks) * 4 + cf) * 1024 + lane * 16) = l;
}

// ---------------- main: MFMA bf16x3 distance argmin --------------------------
// (256,2): (256,4) capped unified VGPR+AGPR -> scratch spill (r4/r7, 1.9 GB HBM).
__global__ __launch_bounds__(256, 2) void vq_gemm_kernel(const float* __restrict__ z,
                                                         char* __restrict__ wsb,
                                                         float* __restrict__ out) {
    __shared__ __align__(16) unsigned char sbuf[2 * 16384 + 4096];
    float* lds_csq = (float*)(sbuf + 32768);

    const int tid  = threadIdx.x;
    const int lane = tid & 63, wid = tid >> 6;
    const int l15  = lane & 15, lg = lane >> 4;

    const float* csq = (const float*)(wsb + CSQ_B);
    #pragma unroll
    for (int i = 0; i < 4; ++i) lds_csq[tid + 256 * i] = csq[tid + 256 * i];

    // A fragments: lane l supplies A[m][k], m = l&15, k = 32*ks + 8*(l>>4)+i
    const int rowbase = blockIdx.x * 256 + wid * 64;
    bf16x8 ah[4][2], al[4][2];
    #pragma unroll
    for (int rf = 0; rf < 4; ++rf) {
        const float* zr = z + (size_t)(rowbase + rf * 16 + l15) * 64 + lg * 8;
        #pragma unroll
        for (int ks = 0; ks < 2; ++ks) {
            float4 a = *reinterpret_cast<const float4*>(zr + ks * 32);
            float4 b = *reinterpret_cast<const float4*>(zr + ks * 32 + 4);
            float f[8] = {a.x, a.y, a.z, a.w, b.x, b.y, b.z, b.w};
            bf16x8 h, l;
            #pragma unroll
            for (int i = 0; i < 8; ++i) {
                __bf16 hv = (__bf16)f[i];
                h[i] = hv;
                l[i] = (__bf16)(f[i] - (float)hv);
            }
            ah[rf][ks] = h; al[rf][ks] = l;
        }
    }

    float m1[16], m2[16]; int i1[16];
    #pragma unroll
    for (int s = 0; s < 16; ++s) { m1[s] = INFINITY; m2[s] = INFINITY; i1[s] = 0; }

    const char* bsrc = wsb + BFRAG_B;
    auto stage = [&](int buf, int t) {
        const char* src = bsrc + (size_t)t * 16384;
        #pragma unroll
        for (int it = 0; it < 4; ++it) {
            GLOAD_LDS16(src + it * 4096 + wid * 1024 + lane * 16,
                        sbuf + buf * 16384 + it * 4096 + wid * 1024);
        }
    };

    stage(0, 0);
    __syncthreads();

    for (int t = 0; t < 16; ++t) {
        if (t < 15) stage((t + 1) & 1, t + 1);
        const unsigned char* B = sbuf + (t & 1) * 16384;
        #pragma unroll
        for (int cf = 0; cf < 4; ++cf) {
            bf16x8 bh0 = *reinterpret_cast<const bf16x8*>(B + (0 * 4 + cf) * 1024 + lane * 16);
            bf16x8 bh1 = *reinterpret_cast<const bf16x8*>(B + (1 * 4 + cf) * 1024 + lane * 16);
            bf16x8 bl0 = *reinterpret_cast<const bf16x8*>(B + (2 * 4 + cf) * 1024 + lane * 16);
            bf16x8 bl1 = *reinterpret_cast<const bf16x8*>(B + (3 * 4 + cf) * 1024 + lane * 16);
            const int code = t * 64 + cf * 16 + l15;
            const float cq = lds_csq[code];
            #pragma unroll
            for (int rf = 0; rf < 4; ++rf) {
                f32x4 acc = {cq, cq, cq, cq};   // C-in = c_sq; B holds -2c
                acc = __builtin_amdgcn_mfma_f32_16x16x32_bf16(ah[rf][0], bh0, acc, 0, 0, 0);
                acc = __builtin_amdgcn_mfma_f32_16x16x32_bf16(ah[rf][1], bh1, acc, 0, 0, 0);
                acc = __builtin_amdgcn_mfma_f32_16x16x32_bf16(al[rf][0], bh0, acc, 0, 0, 0);
                acc = __builtin_amdgcn_mfma_f32_16x16x32_bf16(al[rf][1], bh1, acc, 0, 0, 0);
                acc = __builtin_amdgcn_mfma_f32_16x16x32_bf16(ah[rf][0], bl0, acc, 0, 0, 0);
                acc = __builtin_amdgcn_mfma_f32_16x16x32_bf16(ah[rf][1], bl1, acc, 0, 0, 0);
                #pragma unroll
                for (int r = 0; r < 4; ++r) {
                    float dist = acc[r];
                    int s = rf * 4 + r;
                    bool lt = dist < m1[s];
                    // m2' = min(m2, max(dist, m1)) == med3(dist, m1, m2) given m1<=m2
                    m2[s] = __builtin_amdgcn_fmed3f(dist, m1[s], m2[s]);
                    m1[s] = fminf(m1[s], dist);
                    i1[s] = lt ? code : i1[s];
                }
            }
        }
        __syncthreads();
    }

    // merge across the 16 lanes of each lane-group
    #pragma unroll
    for (int s = 0; s < 16; ++s) {
        #pragma unroll
        for (int off = 1; off < 16; off <<= 1) {
            float om1 = __shfl_xor(m1[s], off);
            float om2 = __shfl_xor(m2[s], off);
            int   oi  = __shfl_xor(i1[s], off);
            bool lt = (om1 < m1[s]) || (om1 == m1[s] && oi < i1[s]);
            m2[s] = fminf(fminf(m2[s], om2), fmaxf(m1[s], om1));
            m1[s] = fminf(m1[s], om1);
            i1[s] = lt ? oi : i1[s];
        }
    }

    if (l15 == 0) {
        int* cnt  = (int*)(wsb + CNT_B);
        int* list = (int*)(wsb + LIST_B);
        #pragma unroll
        for (int rf = 0; rf < 4; ++rf) {
            #pragma unroll
            for (int r = 0; r < 4; ++r) {
                int s = rf * 4 + r;
                int row = rowbase + rf * 16 + lg * 4 + r;
                out[IDX_OFF + row] = (float)i1[s];
                if (m2[s] - m1[s] < MARGIN) {
                    int pos = atomicAdd(cnt, 1);
                    if (pos < N_ROWS) list[pos] = row;
                }
            }
        }
    }
}

// ---------------- exact fp32 re-argmin, coalesced block-per-64-rows ----------
// Old wave-per-row rescore was L2-BW-bound (64 scattered lines per load instr,
// ~4-5 GB traffic ~= the hidden ~190 us). Now: codebook staged coalesced into
// LDS once per block (4 tiles resident; each wave scans its own tile at a
// wave-uniform address -> LDS broadcast), 4 threads per row (one per 256-code
// quarter), exact fp32 chain identical to the round-1-proven argmin.
__global__ __launch_bounds__(256) void rescore_kernel(const float* __restrict__ z,
                                                      const float* __restrict__ cb,
                                                      const char* __restrict__ wsb,
                                                      float* __restrict__ out) {
    __shared__ float4 tile[4][64 * 16];   // 64 KB: 4 resident 64-code tiles
    __shared__ float  csq_sh[4][64];
    __shared__ float  mbest[4][64];
    __shared__ int    midx[4][64];

    int cnt = *(const int*)(wsb + CNT_B);
    if (cnt > N_ROWS) cnt = N_ROWS;
    if (cnt == 0) return;
    const int*   list = (const int*)(wsb + LIST_B);
    const float* csq  = (const float*)(wsb + CSQ_B);

    const int t    = threadIdx.x;
    const int rloc = t & 63;    // row slot within block
    const int q    = t >> 6;    // quarter / wave id: codes [q*256, q*256+256)

    for (long i0 = (long)blockIdx.x * 64; i0 < cnt; i0 += (long)RESCORE_BLOCKS * 64) {
        const long i = i0 + rloc;
        const bool active = (i < cnt);
        const int  row = list[active ? i : (cnt - 1)];

        float4 zr[16];
        const float4* zp = reinterpret_cast<const float4*>(z) + (size_t)row * 16;
        #pragma unroll
        for (int j = 0; j < 16; ++j) zr[j] = zp[j];

        float best = INFINITY; int bi = 0;

        #pragma unroll 1
        for (int j = 0; j < 4; ++j) {     // super-iter: slot s holds tile 4s+j
            __syncthreads();              // prev scan / prev merge done
            #pragma unroll
            for (int s = 0; s < 4; ++s) {
                const float4* src = reinterpret_cast<const float4*>(cb) + (size_t)(s * 4 + j) * 64 * 16;
                #pragma unroll
                for (int u = 0; u < 4; ++u)
                    tile[s][t + 256 * u] = src[t + 256 * u];   // coalesced
            }
            csq_sh[q][rloc] = csq[(q * 4 + j) * 64 + rloc];
            __syncthreads();

            const float4* T = tile[q];    // wave q reads slot q uniformly -> broadcast
            const int cbase = (q * 4 + j) * 64;
            #pragma unroll 2
            for (int k = 0; k < 64; ++k) {
                float d0 = 0.f, d1 = 0.f, d2 = 0.f, d3 = 0.f;
                #pragma unroll
                for (int jj = 0; jj < 16; jj += 4) {
                    float4 c0 = T[k*16+jj+0], c1 = T[k*16+jj+1], c2 = T[k*16+jj+2], c3 = T[k*16+jj+3];
                    d0 = fmaf(zr[jj+0].x, c0.x, fmaf(zr[jj+0].y, c0.y, fmaf(zr[jj+0].z, c0.z, fmaf(zr[jj+0].w, c0.w, d0))));
                    d1 = fmaf(zr[jj+1].x, c1.x, fmaf(zr[jj+1].y, c1.y, fmaf(zr[jj+1].z, c1.z, fmaf(zr[jj+1].w, c1.w, d1))));
                    d2 = fmaf(zr[jj+2].x, c2.x, fmaf(zr[jj+2].y, c2.y, fmaf(zr[jj+2].z, c2.z, fmaf(zr[jj+2].w, c2.w, d2))));
                    d3 = fmaf(zr[jj+3].x, c3.x, fmaf(zr[jj+3].y, c3.y, fmaf(zr[jj+3].z, c3.z, fmaf(zr[jj+3].w, c3.w, d3))));
                }
                float dist = fmaf(-2.f, (d0 + d1) + (d2 + d3), csq_sh[q][k]);
                if (dist < best) { best = dist; bi = cbase + k; }
            }
        }

        mbest[q][rloc] = best; midx[q][rloc] = bi;
        __syncthreads();
        if (q == 0 && active) {
            float b = mbest[0][rloc]; int x = midx[0][rloc];
            #pragma unroll
            for (int s = 1; s < 4; ++s) {
                float ob = mbest[s][rloc]; int ox = midx[s][rloc];
                if (ob < b || (ob == b && ox < x)) { b = ob; x = ox; }
            }
            out[IDX_OFF + row] = (float)x;
        }
    }
}

// ---------------- streaming gather epilogue (round-3 proven) ----------------
__global__ __launch_bounds__(256) void gather_kernel(const float* __restrict__ z,
                                                     const float* __restrict__ cb,
                                                     float* __restrict__ out,
                                                     float* __restrict__ part) {
    const long g4 = (long)blockIdx.x * 256 + threadIdx.x;
    const long g  = g4 * 4;
    const int  r  = (int)(g >> 6);
    const int  d  = (int)(g & 63);
    const int k = (int)out[IDX_OFF + r];
    float4 zv = reinterpret_cast<const float4*>(z)[g4];
    float4 cv = reinterpret_cast<const float4*>(cb)[(long)k * 16 + (d >> 2)];
    float4 st;
    st.x = zv.x + (cv.x - zv.x); st.y = zv.y + (cv.y - zv.y);
    st.z = zv.z + (cv.z - zv.z); st.w = zv.w + (cv.w - zv.w);
    reinterpret_cast<float4*>(out)[g4] = st;
    float* zq = out + ZQ_OFF + g;
    zq[0] = cv.x; zq[1] = cv.y; zq[2] = cv.z; zq[3] = cv.w;
    float dx = cv.x - zv.x, dy = cv.y - zv.y, dz = cv.z - zv.z, dw = cv.w - zv.w;
    float s = fmaf(dx, dx, fmaf(dy, dy, fmaf(dz, dz, dw * dw)));
    #pragma unroll
    for (int off = 32; off > 0; off >>= 1) s += __shfl_down(s, off, 64);
    __shared__ float wsum[4];
    const int lane = threadIdx.x & 63, wid = threadIdx.x >> 6;
    if (lane == 0) wsum[wid] = s;
    __syncthreads();
    if (threadIdx.x == 0)
        part[blockIdx.x] = (wsum[0] + wsum[1]) + (wsum[2] + wsum[3]);
}

__global__ __launch_bounds__(256) void loss_kernel(const float* __restrict__ part,
                                                   float* __restrict__ out) {
    double s = 0.0;
    for (int i = threadIdx.x; i < EPI_BLOCKS; i += 256) s += (double)part[i];
    #pragma unroll
    for (int off = 32; off > 0; off >>= 1) s += __shfl_down(s, off, 64);
    __shared__ double dsum[4];
    const int lane = threadIdx.x & 63, wid = threadIdx.x >> 6;
    if (lane == 0) dsum[wid] = s;
    __syncthreads();
    if (threadIdx.x == 0) {
        double total = (dsum[0] + dsum[1]) + (dsum[2] + dsum[3]);
        out[LOSS_OFF] = (float)(1.25 * (total / (double)((long)N_ROWS * D_DIM)));
    }
}

// ---------------- fallback path (round-1, known-good) ------------------------
__global__ __launch_bounds__(256) void csq_kernel(const float* __restrict__ cb,
                                                  float* __restrict__ ws) {
    int g = blockIdx.x * 256 + threadIdx.x;
    const float4* row = reinterpret_cast<const float4*>(cb) + (size_t)g * (D_DIM / 4);
    float s = 0.f;
    #pragma unroll
    for (int j = 0; j < D_DIM / 4; ++j) {
        float4 v = row[j];
        s = fmaf(v.x, v.x, s); s = fmaf(v.y, v.y, s);
        s = fmaf(v.z, v.z, s); s = fmaf(v.w, v.w, s);
    }
    ws[g] = s;
}

__global__ __launch_bounds__(256) void argmin_old_kernel(const float* __restrict__ z,
                                                         const float* __restrict__ cb,
                                                         const float* __restrict__ ws,
                                                         float* __restrict__ out) {
    __shared__ float4 tile[64 * 16];
    __shared__ float  csq_sh[64];
    const int row = blockIdx.x * 256 + threadIdx.x;
    float4 zr[16];
    const float4* zp = reinterpret_cast<const float4*>(z) + (size_t)row * 16;
    #pragma unroll
    for (int j = 0; j < 16; ++j) zr[j] = zp[j];
    float best = __builtin_inff();
    int   bidx = 0;
    for (int k0 = 0; k0 < K_CODES; k0 += 64) {
        __syncthreads();
        const float4* src = reinterpret_cast<const float4*>(cb) + (size_t)k0 * 16;
        #pragma unroll
        for (int j = 0; j < 4; ++j)
            tile[threadIdx.x + 256 * j] = src[threadIdx.x + 256 * j];
        if (threadIdx.x < 64) csq_sh[threadIdx.x] = ws[k0 + threadIdx.x];
        __syncthreads();
        #pragma unroll 2
        for (int k = 0; k < 64; ++k) {
            float d0 = 0.f, d1 = 0.f, d2 = 0.f, d3 = 0.f;
            #pragma unroll
            for (int j = 0; j < 16; j += 4) {
                float4 c0 = tile[k*16+j+0], c1 = tile[k*16+j+1], c2 = tile[k*16+j+2], c3 = tile[k*16+j+3];
                d0 = fmaf(zr[j+0].x, c0.x, fmaf(zr[j+0].y, c0.y, fmaf(zr[j+0].z, c0.z, fmaf(zr[j+0].w, c0.w, d0))));
                d1 = fmaf(zr[j+1].x, c1.x, fmaf(zr[j+1].y, c1.y, fmaf(zr[j+1].z, c1.z, fmaf(zr[j+1].w, c1.w, d1))));
                d2 = fmaf(zr[j+2].x, c2.x, fmaf(zr[j+2].y, c2.y, fmaf(zr[j+2].z, c2.z, fmaf(zr[j+2].w, c2.w, d2))));
                d3 = fmaf(zr[j+3].x, c3.x, fmaf(zr[j+3].y, c3.y, fmaf(zr[j+3].z, c3.z, fmaf(zr[j+3].w, c3.w, d3))));
            }
            float dist = fmaf(-2.f, (d0 + d1) + (d2 + d3), csq_sh[k]);
            if (dist < best) { best = dist; bidx = k0 + k; }
        }
    }
    out[IDX_OFF + row] = (float)bidx;
}

extern "C" void kernel_launch(void* const* d_in, const int* in_sizes, int n_in,
                              void* d_out, int out_size, void* d_ws, size_t ws_size,
                              hipStream_t stream) {
    (void)in_sizes; (void)n_in; (void)out_size;
    const float* z  = (const float*)d_in[0];
    const float* cb = (const float*)d_in[1];
    float* out = (float*)d_out;
    char*  wsb = (char*)d_ws;
    float* wsf = (float*)d_ws;

    if (ws_size >= WS_NEEDED) {
        fusedprep_kernel<<<32,             256, 0, stream>>>(cb, wsb);
        vq_gemm_kernel  <<<N_ROWS / 256,   256, 0, stream>>>(z, wsb, out);
        rescore_kernel  <<<RESCORE_BLOCKS, 256, 0, stream>>>(z, cb, wsb, out);
        gather_kernel   <<<EPI_BLOCKS,     256, 0, stream>>>(z, cb, out, (float*)(wsb + PART_B));
        loss_kernel     <<<1,              256, 0, stream>>>((const float*)(wsb + PART_B), out);
    } else {
        csq_kernel       <<<K_CODES / 256, 256, 0, stream>>>(cb, wsf);
        argmin_old_kernel<<<N_ROWS / 256,  256, 0, stream>>>(z, cb, wsf, out);
        gather_kernel    <<<EPI_BLOCKS,    256, 0, stream>>>(z, cb, out, wsf + 1024);
        loss_kernel      <<<1,             256, 0, stream>>>(wsf + 1024, out);
    }
}

// Round 10
// 394.560 us; speedup vs baseline: 1.8467x; 1.0024x over previous
//
#include <hip/hip_runtime.h>
#include <hip/hip_bf16.h>

typedef __bf16 bf16x8 __attribute__((ext_vector_type(8)));
typedef float  f32x4  __attribute__((ext_vector_type(4)));

static constexpr int N_ROWS  = 262144;
static constexpr int K_CODES = 1024;
static constexpr int D_DIM   = 64;

// d_out layout (floats): z_q_st[N*D], vq_loss, indices[N], z_q[N*D]
static constexpr long LOSS_OFF = (long)N_ROWS * D_DIM;   // 16777216
static constexpr long IDX_OFF  = LOSS_OFF + 1;           // 16777217
static constexpr long ZQ_OFF   = IDX_OFF + N_ROWS;       // 17039361

// ws byte layout (fast path)
static constexpr size_t CSQ_B   = 0;                              // f32[1024]
static constexpr size_t BFRAG_B = 4096;                           // 16 tiles * 16 KB
static constexpr size_t PART_B  = BFRAG_B + (size_t)16 * 16384;   // 266240: f32[1024]
static constexpr size_t WS_NEEDED = PART_B + 4096;                // ~271 KB

static constexpr float MARGIN = 0.05f;
static constexpr int   EPI_BLOCKS = (N_ROWS * D_DIM) / (256 * 4); // fallback only

#define GLOAD_LDS16(g, l) __builtin_amdgcn_global_load_lds( \
    (const __attribute__((address_space(1))) unsigned int*)(g), \
    (__attribute__((address_space(3))) unsigned int*)(l), 16, 0, 0)

// ---------------- fused prep: csq + bf16 hi/lo of (-2*c) ---------------------
__global__ __launch_bounds__(256) void fusedprep_kernel(const float* __restrict__ cb,
                                                        char* __restrict__ wsb) {
    const int t = blockIdx.x * 256 + threadIdx.x;   // 0..8191 = c*8 + ks*4 + g

    // csq: EXACT same arithmetic order as rounds 1-9 (argmin consistency)
    if (t < K_CODES) {
        const float4* row = reinterpret_cast<const float4*>(cb) + (size_t)t * (D_DIM / 4);
        float s = 0.f;
        #pragma unroll
        for (int j = 0; j < D_DIM / 4; ++j) {
            float4 v = row[j];
            s = fmaf(v.x, v.x, s); s = fmaf(v.y, v.y, s);
            s = fmaf(v.z, v.z, s); s = fmaf(v.w, v.w, s);
        }
        ((float*)(wsb + CSQ_B))[t] = s;
    }

    // fragment split of (-2c): B-frag lane l supplies B[k][n], n=l&15, k=32*ks+8*(l>>4)+i
    const int c  = t >> 3;
    const int ks = (t >> 2) & 1;
    const int g  = t & 3;
    const float* src = cb + (size_t)c * 64 + ks * 32 + g * 8;
    float f[8];
    #pragma unroll
    for (int i = 0; i < 8; ++i) f[i] = -2.0f * src[i];
    bf16x8 h, l;
    #pragma unroll
    for (int i = 0; i < 8; ++i) {
        __bf16 hv = (__bf16)f[i];
        h[i] = hv;
        l[i] = (__bf16)(f[i] - (float)hv);
    }
    const int tile = c >> 6, cf = (c >> 4) & 3, n = c & 15;
    const int lane = g * 16 + n;
    char* base = wsb + BFRAG_B + (size_t)tile * 16384;
    *reinterpret_cast<bf16x8*>(base + ((0 * 2 + ks) * 4 + cf) * 1024 + lane * 16) = h;
    *reinterpret_cast<bf16x8*>(base + ((1 * 2 + ks) * 4 + cf) * 1024 + lane * 16) = l;
}

// ---------------- mega: MFMA argmin + in-wave exact rescore + epilogue -------
// (256,2): (256,4) caps unified VGPR+AGPR at ~128 -> scratch spill (r4/r7,
// 1.9 GB HBM traffic). (256,2) is spill-free (r3/r8/r9: 130 us gemm phase).
__global__ __launch_bounds__(256, 2) void vq_mega_kernel(const float* __restrict__ z,
                                                         const float* __restrict__ cb,
                                                         const char* __restrict__ wsb,
                                                         float* __restrict__ out,
                                                         float* __restrict__ part) {
    __shared__ __align__(16) unsigned char sbuf[2 * 16384 + 4096];
    float* lds_csq = (float*)(sbuf + 32768);            // alive through rescore
    // overlays on dead buf0 after the MFMA loop:
    int*                idx_sh = (int*)sbuf;            // [256]
    unsigned long long* msk_sh = (unsigned long long*)(sbuf + 1024);  // [16]
    float*              bsum   = (float*)(sbuf + 1152); // [4]

    const int tid  = threadIdx.x;
    const int lane = tid & 63, wid = tid >> 6;
    const int l15  = lane & 15, lg = lane >> 4;

    const float* csq = (const float*)(wsb + CSQ_B);
    #pragma unroll
    for (int i = 0; i < 4; ++i) lds_csq[tid + 256 * i] = csq[tid + 256 * i];

    // A fragments: lane l supplies A[m][k], m = l&15, k = 32*ks + 8*(l>>4)+i
    const int blockbase = blockIdx.x * 256;
    const int rowbase   = blockbase + wid * 64;
    bf16x8 ah[4][2], al[4][2];
    #pragma unroll
    for (int rf = 0; rf < 4; ++rf) {
        const float* zr = z + (size_t)(rowbase + rf * 16 + l15) * 64 + lg * 8;
        #pragma unroll
        for (int ks = 0; ks < 2; ++ks) {
            float4 a = *reinterpret_cast<const float4*>(zr + ks * 32);
            float4 b = *reinterpret_cast<const float4*>(zr + ks * 32 + 4);
            float f[8] = {a.x, a.y, a.z, a.w, b.x, b.y, b.z, b.w};
            bf16x8 h, l;
            #pragma unroll
            for (int i = 0; i < 8; ++i) {
                __bf16 hv = (__bf16)f[i];
                h[i] = hv;
                l[i] = (__bf16)(f[i] - (float)hv);
            }
            ah[rf][ks] = h; al[rf][ks] = l;
        }
    }

    float m1[16], m2[16]; int i1[16];
    #pragma unroll
    for (int s = 0; s < 16; ++s) { m1[s] = INFINITY; m2[s] = INFINITY; i1[s] = 0; }

    const char* bsrc = wsb + BFRAG_B;
    auto stage = [&](int buf, int t) {
        const char* src = bsrc + (size_t)t * 16384;
        #pragma unroll
        for (int it = 0; it < 4; ++it) {
            GLOAD_LDS16(src + it * 4096 + wid * 1024 + lane * 16,
                        sbuf + buf * 16384 + it * 4096 + wid * 1024);
        }
    };

    stage(0, 0);
    __syncthreads();

    for (int t = 0; t < 16; ++t) {
        if (t < 15) stage((t + 1) & 1, t + 1);
        const unsigned char* B = sbuf + (t & 1) * 16384;
        #pragma unroll
        for (int cf = 0; cf < 4; ++cf) {
            bf16x8 bh0 = *reinterpret_cast<const bf16x8*>(B + (0 * 4 + cf) * 1024 + lane * 16);
            bf16x8 bh1 = *reinterpret_cast<const bf16x8*>(B + (1 * 4 + cf) * 1024 + lane * 16);
            bf16x8 bl0 = *reinterpret_cast<const bf16x8*>(B + (2 * 4 + cf) * 1024 + lane * 16);
            bf16x8 bl1 = *reinterpret_cast<const bf16x8*>(B + (3 * 4 + cf) * 1024 + lane * 16);
            const int code = t * 64 + cf * 16 + l15;
            const float cq = lds_csq[code];
            #pragma unroll
            for (int rf = 0; rf < 4; ++rf) {
                f32x4 acc = {cq, cq, cq, cq};   // C-in = c_sq; B holds -2c
                acc = __builtin_amdgcn_mfma_f32_16x16x32_bf16(ah[rf][0], bh0, acc, 0, 0, 0);
                acc = __builtin_amdgcn_mfma_f32_16x16x32_bf16(ah[rf][1], bh1, acc, 0, 0, 0);
                acc = __builtin_amdgcn_mfma_f32_16x16x32_bf16(al[rf][0], bh0, acc, 0, 0, 0);
                acc = __builtin_amdgcn_mfma_f32_16x16x32_bf16(al[rf][1], bh1, acc, 0, 0, 0);
                acc = __builtin_amdgcn_mfma_f32_16x16x32_bf16(ah[rf][0], bl0, acc, 0, 0, 0);
                acc = __builtin_amdgcn_mfma_f32_16x16x32_bf16(ah[rf][1], bl1, acc, 0, 0, 0);
                #pragma unroll
                for (int r = 0; r < 4; ++r) {
                    float dist = acc[r];
                    int s = rf * 4 + r;
                    bool lt = dist < m1[s];
                    m2[s] = __builtin_amdgcn_fmed3f(dist, m1[s], m2[s]);
                    m1[s] = fminf(m1[s], dist);
                    i1[s] = lt ? code : i1[s];
                }
            }
        }
        __syncthreads();   // after t=15: ALL waves done with all sbuf reads
    }

    // merge across the 16 lanes of each lane-group
    #pragma unroll
    for (int s = 0; s < 16; ++s) {
        #pragma unroll
        for (int off = 1; off < 16; off <<= 1) {
            float om1 = __shfl_xor(m1[s], off);
            float om2 = __shfl_xor(m2[s], off);
            int   oi  = __shfl_xor(i1[s], off);
            bool lt = (om1 < m1[s]) || (om1 == m1[s] && oi < i1[s]);
            m2[s] = fminf(fminf(m2[s], om2), fmaxf(m1[s], om1));
            m1[s] = fminf(m1[s], om1);
            i1[s] = lt ? oi : i1[s];
        }
    }

    // publish approx indices + per-wave flag mask (own-wave data only)
    if (l15 == 0) {
        unsigned long long m = 0;
        #pragma unroll
        for (int rf = 0; rf < 4; ++rf) {
            #pragma unroll
            for (int r = 0; r < 4; ++r) {
                int s = rf * 4 + r;
                int rowpos = rf * 16 + lg * 4 + r;
                idx_sh[wid * 64 + rowpos] = i1[s];
                if (m2[s] - m1[s] < MARGIN) m |= 1ull << rowpos;
            }
        }
        msk_sh[wid * 4 + lg] = m;
    }
    // same-wave LDS write->read (lockstep); no block barrier needed until
    // cross-wave reads below.

    // in-wave exact fp32 rescore of this wave's flagged rows
    unsigned long long mask = msk_sh[wid * 4 + 0] | msk_sh[wid * 4 + 1]
                            | msk_sh[wid * 4 + 2] | msk_sh[wid * 4 + 3];
    while (mask) {
        const int rowpos = __builtin_ctzll(mask);
        mask &= mask - 1;
        const int row = rowbase + rowpos;

        float4 zr[16];
        const float4* zp = reinterpret_cast<const float4*>(z) + (size_t)row * 16;
        #pragma unroll
        for (int j = 0; j < 16; ++j) zr[j] = zp[j];   // wave-uniform, broadcast

        float best = INFINITY; int bi = 0;
        for (int k = lane; k < K_CODES; k += 64) {
            const float4* cp = reinterpret_cast<const float4*>(cb) + (size_t)k * 16;
            float d0 = 0.f, d1 = 0.f, d2 = 0.f, d3 = 0.f;
            #pragma unroll
            for (int j = 0; j < 16; j += 4) {
                float4 c0 = cp[j + 0], c1 = cp[j + 1], c2 = cp[j + 2], c3 = cp[j + 3];
                d0 = fmaf(zr[j+0].x, c0.x, fmaf(zr[j+0].y, c0.y, fmaf(zr[j+0].z, c0.z, fmaf(zr[j+0].w, c0.w, d0))));
                d1 = fmaf(zr[j+1].x, c1.x, fmaf(zr[j+1].y, c1.y, fmaf(zr[j+1].z, c1.z, fmaf(zr[j+1].w, c1.w, d1))));
                d2 = fmaf(zr[j+2].x, c2.x, fmaf(zr[j+2].y, c2.y, fmaf(zr[j+2].z, c2.z, fmaf(zr[j+2].w, c2.w, d2))));
                d3 = fmaf(zr[j+3].x, c3.x, fmaf(zr[j+3].y, c3.y, fmaf(zr[j+3].z, c3.z, fmaf(zr[j+3].w, c3.w, d3))));
            }
            float dist = fmaf(-2.f, (d0 + d1) + (d2 + d3), lds_csq[k]);
            if (dist < best) { best = dist; bi = k; }
        }
        #pragma unroll
        for (int off = 1; off < 64; off <<= 1) {
            float ob = __shfl_xor(best, off);
            int   oi = __shfl_xor(bi, off);
            if (ob < best || (ob == best && oi < bi)) { best = ob; bi = oi; }
        }
        if (lane == 0) idx_sh[wid * 64 + rowpos] = bi;
    }
    __syncthreads();   // idx_sh final; cross-wave reads OK

    // coalesced index store (reads cross-wave idx_sh)
    out[IDX_OFF + blockbase + tid] = (float)idx_sh[tid];

    // fused epilogue (validated in r4): this wave's 64 rows -> z_q_st, z_q, loss
    float lsum = 0.f;
    #pragma unroll 4
    for (int rl = 0; rl < 64; ++rl) {
        const int row = rowbase + rl;
        const int k   = idx_sh[wid * 64 + rl];
        float zv = z [(size_t)row * 64 + lane];
        float cv = cb[(size_t)k   * 64 + lane];
        out[(size_t)row * 64 + lane]          = zv + (cv - zv);   // z_q_st
        out[ZQ_OFF + (size_t)row * 64 + lane] = cv;               // z_q
        float d = cv - zv;
        lsum = fmaf(d, d, lsum);
    }
    #pragma unroll
    for (int off = 32; off > 0; off >>= 1) lsum += __shfl_down(lsum, off, 64);
    if (lane == 0) bsum[wid] = lsum;
    __syncthreads();
    if (tid == 0)
        part[blockIdx.x] = (bsum[0] + bsum[1]) + (bsum[2] + bsum[3]);
}

// ---------------- loss finalize ---------------------------------------------
__global__ __launch_bounds__(256) void loss_kernel(const float* __restrict__ part,
                                                   float* __restrict__ out) {
    double s = 0.0;
    for (int i = threadIdx.x; i < 1024; i += 256) s += (double)part[i];
    #pragma unroll
    for (int off = 32; off > 0; off >>= 1) s += __shfl_down(s, off, 64);
    __shared__ double dsum[4];
    const int lane = threadIdx.x & 63, wid = threadIdx.x >> 6;
    if (lane == 0) dsum[wid] = s;
    __syncthreads();
    if (threadIdx.x == 0) {
        double total = (dsum[0] + dsum[1]) + (dsum[2] + dsum[3]);
        out[LOSS_OFF] = (float)(1.25 * (total / (double)((long)N_ROWS * D_DIM)));
    }
}

// ---------------- fallback path (round-1, known-good) ------------------------
__global__ __launch_bounds__(256) void csq_kernel(const float* __restrict__ cb,
                                                  float* __restrict__ ws) {
    int g = blockIdx.x * 256 + threadIdx.x;
    const float4* row = reinterpret_cast<const float4*>(cb) + (size_t)g * (D_DIM / 4);
    float s = 0.f;
    #pragma unroll
    for (int j = 0; j < D_DIM / 4; ++j) {
        float4 v = row[j];
        s = fmaf(v.x, v.x, s); s = fmaf(v.y, v.y, s);
        s = fmaf(v.z, v.z, s); s = fmaf(v.w, v.w, s);
    }
    ws[g] = s;
}

__global__ __launch_bounds__(256) void argmin_old_kernel(const float* __restrict__ z,
                                                         const float* __restrict__ cb,
                                                         const float* __restrict__ ws,
                                                         float* __restrict__ out) {
    __shared__ float4 tile[64 * 16];
    __shared__ float  csq_sh[64];
    const int row = blockIdx.x * 256 + threadIdx.x;
    float4 zr[16];
    const float4* zp = reinterpret_cast<const float4*>(z) + (size_t)row * 16;
    #pragma unroll
    for (int j = 0; j < 16; ++j) zr[j] = zp[j];
    float best = __builtin_inff();
    int   bidx = 0;
    for (int k0 = 0; k0 < K_CODES; k0 += 64) {
        __syncthreads();
        const float4* src = reinterpret_cast<const float4*>(cb) + (size_t)k0 * 16;
        #pragma unroll
        for (int j = 0; j < 4; ++j)
            tile[threadIdx.x + 256 * j] = src[threadIdx.x + 256 * j];
        if (threadIdx.x < 64) csq_sh[threadIdx.x] = ws[k0 + threadIdx.x];
        __syncthreads();
        #pragma unroll 2
        for (int k = 0; k < 64; ++k) {
            float d0 = 0.f, d1 = 0.f, d2 = 0.f, d3 = 0.f;
            #pragma unroll
            for (int j = 0; j < 16; j += 4) {
                float4 c0 = tile[k*16+j+0], c1 = tile[k*16+j+1], c2 = tile[k*16+j+2], c3 = tile[k*16+j+3];
                d0 = fmaf(zr[j+0].x, c0.x, fmaf(zr[j+0].y, c0.y, fmaf(zr[j+0].z, c0.z, fmaf(zr[j+0].w, c0.w, d0))));
                d1 = fmaf(zr[j+1].x, c1.x, fmaf(zr[j+1].y, c1.y, fmaf(zr[j+1].z, c1.z, fmaf(zr[j+1].w, c1.w, d1))));
                d2 = fmaf(zr[j+2].x, c2.x, fmaf(zr[j+2].y, c2.y, fmaf(zr[j+2].z, c2.z, fmaf(zr[j+2].w, c2.w, d2))));
                d3 = fmaf(zr[j+3].x, c3.x, fmaf(zr[j+3].y, c3.y, fmaf(zr[j+3].z, c3.z, fmaf(zr[j+3].w, c3.w, d3))));
            }
            float dist = fmaf(-2.f, (d0 + d1) + (d2 + d3), csq_sh[k]);
            if (dist < best) { best = dist; bidx = k0 + k; }
        }
    }
    out[IDX_OFF + row] = (float)bidx;
}

__global__ __launch_bounds__(256) void gather_kernel(const float* __restrict__ z,
                                                     const float* __restrict__ cb,
                                                     float* __restrict__ out,
                                                     float* __restrict__ part) {
    const long g4 = (long)blockIdx.x * 256 + threadIdx.x;
    const long g  = g4 * 4;
    const int  r  = (int)(g >> 6);
    const int  d  = (int)(g & 63);
    const int k = (int)out[IDX_OFF + r];
    float4 zv = reinterpret_cast<const float4*>(z)[g4];
    float4 cv = reinterpret_cast<const float4*>(cb)[(long)k * 16 + (d >> 2)];
    float4 st;
    st.x = zv.x + (cv.x - zv.x); st.y = zv.y + (cv.y - zv.y);
    st.z = zv.z + (cv.z - zv.z); st.w = zv.w + (cv.w - zv.w);
    reinterpret_cast<float4*>(out)[g4] = st;
    float* zq = out + ZQ_OFF + g;
    zq[0] = cv.x; zq[1] = cv.y; zq[2] = cv.z; zq[3] = cv.w;
    float dx = cv.x - zv.x, dy = cv.y - zv.y, dz = cv.z - zv.z, dw = cv.w - zv.w;
    float s = fmaf(dx, dx, fmaf(dy, dy, fmaf(dz, dz, dw * dw)));
    #pragma unroll
    for (int off = 32; off > 0; off >>= 1) s += __shfl_down(s, off, 64);
    __shared__ float wsum[4];
    const int lane = threadIdx.x & 63, wid = threadIdx.x >> 6;
    if (lane == 0) wsum[wid] = s;
    __syncthreads();
    if (threadIdx.x == 0)
        part[blockIdx.x] = (wsum[0] + wsum[1]) + (wsum[2] + wsum[3]);
}

__global__ __launch_bounds__(256) void loss_old_kernel(const float* __restrict__ part,
                                                       float* __restrict__ out) {
    double s = 0.0;
    for (int i = threadIdx.x; i < EPI_BLOCKS; i += 256) s += (double)part[i];
    #pragma unroll
    for (int off = 32; off > 0; off >>= 1) s += __shfl_down(s, off, 64);
    __shared__ double dsum[4];
    const int lane = threadIdx.x & 63, wid = threadIdx.x >> 6;
    if (lane == 0) dsum[wid] = s;
    __syncthreads();
    if (threadIdx.x == 0) {
        double total = (dsum[0] + dsum[1]) + (dsum[2] + dsum[3]);
        out[LOSS_OFF] = (float)(1.25 * (total / (double)((long)N_ROWS * D_DIM)));
    }
}

extern "C" void kernel_launch(void* const* d_in, const int* in_sizes, int n_in,
                              void* d_out, int out_size, void* d_ws, size_t ws_size,
                              hipStream_t stream) {
    (void)in_sizes; (void)n_in; (void)out_size;
    const float* z  = (const float*)d_in[0];
    const float* cb = (const float*)d_in[1];
    float* out = (float*)d_out;
    char*  wsb = (char*)d_ws;
    float* wsf = (float*)d_ws;

    if (ws_size >= WS_NEEDED) {
        fusedprep_kernel<<<32,           256, 0, stream>>>(cb, wsb);
        vq_mega_kernel  <<<N_ROWS / 256, 256, 0, stream>>>(z, cb, wsb, out,
                                                           (float*)(wsb + PART_B));
        loss_kernel     <<<1,            256, 0, stream>>>((const float*)(wsb + PART_B), out);
    } else {
        csq_kernel       <<<K_CODES / 256, 256, 0, stream>>>(cb, wsf);
        argmin_old_kernel<<<N_ROWS / 256,  256, 0, stream>>>(z, cb, wsf, out);
        gather_kernel    <<<EPI_BLOCKS,    256, 0, stream>>>(z, cb, out, wsf + 1024);
        loss_old_kernel  <<<1,             256, 0, stream>>>(wsf + 1024, out);
    }
}